// Round 1
// baseline (7664.737 us; speedup 1.0000x reference)
//
#include <hip/hip_runtime.h>
#include <hip/hip_bf16.h>
#include <math.h>

#define BB 2
#define TT 1024
#define DD 1024
#define NH 16
#define KVHN 4
#define HDIM 64
#define NL 4
#define II 2730
#define NTOK (BB * TT)

// ---------------- rope sin/cos table ----------------
__global__ void rope_table_k(float* __restrict__ st, float* __restrict__ ct) {
    int i = blockIdx.x * 256 + threadIdx.x;
    if (i >= TT * HDIM) return;
    int t = i >> 6, d = i & 63;
    float freq = powf(10000.0f, (float)(d & 31) / 32.0f);
    float ang = (float)t / freq;
    st[i] = sinf(ang);
    ct[i] = cosf(ang);
}

// ---------------- embedding gather ----------------
__global__ __launch_bounds__(256) void embed_k(const int* __restrict__ idx,
                                               const float* __restrict__ wte,
                                               float* __restrict__ x) {
    int row = blockIdx.x;
    int tok = idx[row];
    const float4* src = (const float4*)(wte + (size_t)tok * DD);
    float4* dst = (float4*)(x + (size_t)row * DD);
    dst[threadIdx.x] = src[threadIdx.x];
}

// ---------------- rmsnorm ----------------
__global__ __launch_bounds__(256) void rmsnorm_k(const float* __restrict__ x,
                                                 const float* __restrict__ w,
                                                 float* __restrict__ o) {
    int row = blockIdx.x;
    float4 v = ((const float4*)(x + (size_t)row * DD))[threadIdx.x];
    float s = v.x * v.x + v.y * v.y + v.z * v.z + v.w * v.w;
#pragma unroll
    for (int off = 32; off > 0; off >>= 1) s += __shfl_down(s, off);
    __shared__ float red[4];
    if ((threadIdx.x & 63) == 0) red[threadIdx.x >> 6] = s;
    __syncthreads();
    float tot = red[0] + red[1] + red[2] + red[3];
    float r = rsqrtf(tot * (1.0f / DD) + 1e-6f);
    float4 wv = ((const float4*)w)[threadIdx.x];
    float4 ov;
    ov.x = v.x * r * wv.x;
    ov.y = v.y * r * wv.y;
    ov.z = v.z * r * wv.z;
    ov.w = v.w * r * wv.w;
    ((float4*)(o + (size_t)row * DD))[threadIdx.x] = ov;
}

// ---------------- rope apply (in place), GPT-NeoX half rotation ----------------
__global__ void rope_k(float* __restrict__ buf, const float* __restrict__ st,
                       const float* __restrict__ ct, int stride, int nheads) {
    int i = blockIdx.x * 256 + threadIdx.x;
    int per_row = 32 * nheads;
    int total = NTOK * per_row;
    if (i >= total) return;
    int row = i / per_row;
    int rem = i - row * per_row;
    int hh = rem >> 5;
    int d = rem & 31;
    int t = row & (TT - 1);
    float* p = buf + (size_t)row * stride + hh * HDIM;
    float x0 = p[d], x1 = p[d + 32];
    float c = ct[t * HDIM + d], s = st[t * HDIM + d];
    p[d] = x0 * c - x1 * s;
    p[d + 32] = x1 * c + x0 * s;
}

// ---------------- flash attention (fp32, causal, GQA h%4) ----------------
__global__ __launch_bounds__(256) void attn_k(const float* __restrict__ q,
                                              const float* __restrict__ kv,
                                              float* __restrict__ y) {
    int qt = blockIdx.x;  // 0..15 query tile of 64
    int h = blockIdx.y;   // 0..15
    int b = blockIdx.z;   // 0..1
    int kvh = h & (KVHN - 1);

    __shared__ float Qs[64][65];
    __shared__ float Ks[32][65];
    __shared__ float Vs[32][65];
    __shared__ float Ss[64][33];

    int tid = threadIdx.x;
    for (int e = tid; e < 64 * 64; e += 256) {
        int r = e >> 6, d = e & 63;
        Qs[r][d] = q[(size_t)(b * TT + qt * 64 + r) * DD + h * HDIM + d];
    }

    int r = tid >> 2;         // query row within tile
    int g = (tid & 3) << 4;   // output dim base (16 dims per thread)
    int jb = (tid & 3) << 3;  // score col base (8 cols per thread)

    float m = -INFINITY, l = 0.0f;
    float o[16];
#pragma unroll
    for (int i = 0; i < 16; i++) o[i] = 0.0f;

    int ktmax = 2 * qt + 1;  // key tiles of 32 covering keys <= qt*64+63
    for (int kt = 0; kt <= ktmax; ++kt) {
        __syncthreads();
        for (int e = tid; e < 32 * 64; e += 256) {
            int j = e >> 6, d = e & 63;
            size_t base = (size_t)(b * TT + kt * 32 + j) * (2 * KVHN * HDIM);
            Ks[j][d] = kv[base + kvh * HDIM + d];
            Vs[j][d] = kv[base + KVHN * HDIM + kvh * HDIM + d];
        }
        __syncthreads();
        for (int jj = 0; jj < 8; jj++) {
            int j = jb + jj;
            float s = 0.0f;
#pragma unroll
            for (int d = 0; d < 64; d++) s += Qs[r][d] * Ks[j][d];
            s *= 0.125f;
            if (kt * 32 + j > qt * 64 + r) s = -INFINITY;
            Ss[r][j] = s;
        }
        __syncthreads();
        float mt = m;
#pragma unroll
        for (int j = 0; j < 32; j++) mt = fmaxf(mt, Ss[r][j]);
        float scale = expf(m - mt);
        float lsum = 0.0f;
#pragma unroll
        for (int i = 0; i < 16; i++) o[i] *= scale;
        for (int j = 0; j < 32; j++) {
            float p = expf(Ss[r][j] - mt);
            lsum += p;
#pragma unroll
            for (int i = 0; i < 16; i++) o[i] += p * Vs[j][g + i];
        }
        l = l * scale + lsum;
        m = mt;
    }
    float inv = 1.0f / l;
    size_t orow = (size_t)(b * TT + qt * 64 + r) * DD + h * HDIM + g;
#pragma unroll
    for (int i = 0; i < 16; i++) y[orow + i] = o[i] * inv;
}

// ---------------- silu(g) * u -> g ----------------
__global__ void silu_mul_k(float* __restrict__ g, const float* __restrict__ u, int n) {
    int i = blockIdx.x * 256 + threadIdx.x;
    if (i >= n) return;
    float gv = g[i];
    float s = gv / (1.0f + expf(-gv));
    g[i] = s * u[i];
}

// ---------------- tiled SGEMM: C[N,M] = A[N,K] @ W[M,K]^T (+res) ----------------
// 64x64 tile, 4x4 microtile, BK=16, 256 threads. N must be multiple of 64.
template <int RES>
__global__ __launch_bounds__(256) void sgemm_k(const float* __restrict__ A,
                                               const float* __restrict__ W,
                                               const float* __restrict__ res,
                                               float* __restrict__ C,
                                               int N, int M, int K) {
    __shared__ float As[16][68];
    __shared__ float Bs[16][68];

    int tid = threadIdx.x;
    int m0 = blockIdx.x * 64;
    int n0 = blockIdx.y * 64;

    int lr = tid >> 2;          // 0..63 loader row
    int lk = (tid & 3) << 2;    // 0,4,8,12 loader k base
    int tm = (tid & 15) << 2;   // acc row base within tile
    int tn = (tid >> 4) << 2;   // acc col base within tile

    float acc[4][4] = {{0.0f}};

    const float* Arow = A + (size_t)(n0 + lr) * K;
    const float* Wrow = W + (size_t)(m0 + lr) * K;
    bool wok = (m0 + lr) < M;

    for (int k0 = 0; k0 < K; k0 += 16) {
        int k = k0 + lk;
        float a0 = 0, a1 = 0, a2 = 0, a3 = 0, b0 = 0, b1 = 0, b2 = 0, b3 = 0;
        if (k + 4 <= K) {
            a0 = Arow[k]; a1 = Arow[k + 1]; a2 = Arow[k + 2]; a3 = Arow[k + 3];
            if (wok) { b0 = Wrow[k]; b1 = Wrow[k + 1]; b2 = Wrow[k + 2]; b3 = Wrow[k + 3]; }
        } else {
            if (k < K)     { a0 = Arow[k];     if (wok) b0 = Wrow[k]; }
            if (k + 1 < K) { a1 = Arow[k + 1]; if (wok) b1 = Wrow[k + 1]; }
            if (k + 2 < K) { a2 = Arow[k + 2]; if (wok) b2 = Wrow[k + 2]; }
            if (k + 3 < K) { a3 = Arow[k + 3]; if (wok) b3 = Wrow[k + 3]; }
        }
        __syncthreads();
        As[lk + 0][lr] = a0; As[lk + 1][lr] = a1; As[lk + 2][lr] = a2; As[lk + 3][lr] = a3;
        Bs[lk + 0][lr] = b0; Bs[lk + 1][lr] = b1; Bs[lk + 2][lr] = b2; Bs[lk + 3][lr] = b3;
        __syncthreads();
#pragma unroll
        for (int kk = 0; kk < 16; kk++) {
            float4 a = *(const float4*)&As[kk][tm];
            float4 b = *(const float4*)&Bs[kk][tn];
            acc[0][0] += a.x * b.x; acc[0][1] += a.x * b.y; acc[0][2] += a.x * b.z; acc[0][3] += a.x * b.w;
            acc[1][0] += a.y * b.x; acc[1][1] += a.y * b.y; acc[1][2] += a.y * b.z; acc[1][3] += a.y * b.w;
            acc[2][0] += a.z * b.x; acc[2][1] += a.z * b.y; acc[2][2] += a.z * b.z; acc[2][3] += a.z * b.w;
            acc[3][0] += a.w * b.x; acc[3][1] += a.w * b.y; acc[3][2] += a.w * b.z; acc[3][3] += a.w * b.w;
        }
    }

#pragma unroll
    for (int i = 0; i < 4; i++) {
        size_t n = n0 + tm + i;
#pragma unroll
        for (int j = 0; j < 4; j++) {
            int mm = m0 + tn + j;
            if (mm < M) {
                size_t off = n * (size_t)M + mm;
                float v = acc[i][j];
                if (RES) v += res[off];
                C[off] = v;
            }
        }
    }
}

extern "C" void kernel_launch(void* const* d_in, const int* in_sizes, int n_in,
                              void* d_out, int out_size, void* d_ws, size_t ws_size,
                              hipStream_t stream) {
    const int* idx    = (const int*)d_in[0];
    const float* wte  = (const float*)d_in[1];
    const float* Wq   = (const float*)d_in[2];
    const float* Wkv  = (const float*)d_in[3];
    const float* Wo   = (const float*)d_in[4];
    const float* Wg   = (const float*)d_in[5];
    const float* Wu   = (const float*)d_in[6];
    const float* Wd   = (const float*)d_in[7];
    const float* rms1 = (const float*)d_in[8];
    const float* rms2 = (const float*)d_in[9];
    const float* rmsf = (const float*)d_in[10];
    float* out = (float*)d_out;

    float* ws = (float*)d_ws;
    float* x   = ws;                           // 2048*1024
    float* xn  = x + (size_t)NTOK * DD;        // 2048*1024
    float* qb  = xn + (size_t)NTOK * DD;       // 2048*1024
    float* kvb = qb + (size_t)NTOK * DD;       // 2048*512
    float* yb  = kvb + (size_t)NTOK * 512;     // 2048*1024
    float* gb  = yb + (size_t)NTOK * DD;       // 2048*2730
    float* ub  = gb + (size_t)NTOK * II;       // 2048*2730
    float* st  = ub + (size_t)NTOK * II;       // 1024*64
    float* ct  = st + (size_t)TT * HDIM;       // 1024*64
    // total ~79.2 MiB of workspace

    rope_table_k<<<(TT * HDIM + 255) / 256, 256, 0, stream>>>(st, ct);
    embed_k<<<NTOK, 256, 0, stream>>>(idx, wte, x);

    for (int l = 0; l < NL; ++l) {
        rmsnorm_k<<<NTOK, 256, 0, stream>>>(x, rms1 + (size_t)l * DD, xn);
        sgemm_k<0><<<dim3(1024 / 64, NTOK / 64), 256, 0, stream>>>(
            xn, Wq + (size_t)l * DD * DD, nullptr, qb, NTOK, 1024, 1024);
        sgemm_k<0><<<dim3(512 / 64, NTOK / 64), 256, 0, stream>>>(
            xn, Wkv + (size_t)l * 512 * DD, nullptr, kvb, NTOK, 512, 1024);
        rope_k<<<(NTOK * NH * 32 + 255) / 256, 256, 0, stream>>>(qb, st, ct, DD, NH);
        rope_k<<<(NTOK * KVHN * 32 + 255) / 256, 256, 0, stream>>>(kvb, st, ct, 512, KVHN);
        attn_k<<<dim3(TT / 64, NH, BB), 256, 0, stream>>>(qb, kvb, yb);
        sgemm_k<1><<<dim3(1024 / 64, NTOK / 64), 256, 0, stream>>>(
            yb, Wo + (size_t)l * DD * DD, x, x, NTOK, 1024, 1024);
        rmsnorm_k<<<NTOK, 256, 0, stream>>>(x, rms2 + (size_t)l * DD, xn);
        sgemm_k<0><<<dim3((II + 63) / 64, NTOK / 64), 256, 0, stream>>>(
            xn, Wg + (size_t)l * II * DD, nullptr, gb, NTOK, II, 1024);
        sgemm_k<0><<<dim3((II + 63) / 64, NTOK / 64), 256, 0, stream>>>(
            xn, Wu + (size_t)l * II * DD, nullptr, ub, NTOK, II, 1024);
        silu_mul_k<<<(NTOK * II + 255) / 256, 256, 0, stream>>>(gb, ub, NTOK * II);
        sgemm_k<1><<<dim3(1024 / 64, NTOK / 64), 256, 0, stream>>>(
            gb, Wd + (size_t)l * DD * II, x, x, NTOK, 1024, II);
    }
    rmsnorm_k<<<NTOK, 256, 0, stream>>>(x, rmsf, xn);
    sgemm_k<0><<<dim3(32000 / 64, NTOK / 64), 256, 0, stream>>>(
        xn, wte, nullptr, out, NTOK, 32000, 1024);
}

// Round 2
// 3878.312 us; speedup vs baseline: 1.9763x; 1.9763x over previous
//
#include <hip/hip_runtime.h>
#include <hip/hip_bf16.h>
#include <math.h>

#define BB 2
#define TT 1024
#define DD 1024
#define NH 16
#define KVHN 4
#define NL 4
#define II 2730
#define IIP 2816          // padded intermediate (multiple of 128)
#define NTOK (BB * TT)
#define QKVD 1536         // fused q(1024)+kv(512) width

typedef __hip_bfloat16 bf16;
typedef __attribute__((ext_vector_type(8))) short bf16x8;
typedef __attribute__((ext_vector_type(4))) float f32x4;

#define GLOAD16(gp, lp)                                                        \
    __builtin_amdgcn_global_load_lds(                                          \
        (const __attribute__((address_space(1))) unsigned int*)(gp),           \
        (__attribute__((address_space(3))) unsigned int*)(lp), 16, 0, 0)

// ---------------- rope sin/cos table ----------------
__global__ void rope_table_k(float* __restrict__ st, float* __restrict__ ct) {
    int i = blockIdx.x * 256 + threadIdx.x;
    if (i >= TT * 64) return;
    int t = i >> 6, d = i & 63;
    float freq = powf(10000.0f, (float)(d & 31) / 32.0f);
    float ang = (float)t / freq;
    st[i] = sinf(ang);
    ct[i] = cosf(ang);
}

// ---------------- embedding gather (fp32 residual) ----------------
__global__ __launch_bounds__(256) void embed_k(const int* __restrict__ idx,
                                               const float* __restrict__ wte,
                                               float* __restrict__ x) {
    int row = blockIdx.x;
    int tok = idx[row];
    const float4* src = (const float4*)(wte + (size_t)tok * DD);
    float4* dst = (float4*)(x + (size_t)row * DD);
    dst[threadIdx.x] = src[threadIdx.x];
}

// ---------------- rmsnorm: fp32 in -> bf16 out ----------------
__global__ __launch_bounds__(256) void rmsnorm_k(const float* __restrict__ x,
                                                 const float* __restrict__ w,
                                                 bf16* __restrict__ o) {
    int row = blockIdx.x;
    float4 v = ((const float4*)(x + (size_t)row * DD))[threadIdx.x];
    float s = v.x * v.x + v.y * v.y + v.z * v.z + v.w * v.w;
#pragma unroll
    for (int off = 32; off > 0; off >>= 1) s += __shfl_down(s, off);
    __shared__ float red[4];
    if ((threadIdx.x & 63) == 0) red[threadIdx.x >> 6] = s;
    __syncthreads();
    float tot = red[0] + red[1] + red[2] + red[3];
    float r = rsqrtf(tot * (1.0f / DD) + 1e-6f);
    float4 wv = ((const float4*)w)[threadIdx.x];
    size_t base = (size_t)row * DD + threadIdx.x * 4;
    o[base + 0] = __float2bfloat16(v.x * r * wv.x);
    o[base + 1] = __float2bfloat16(v.y * r * wv.y);
    o[base + 2] = __float2bfloat16(v.z * r * wv.z);
    o[base + 3] = __float2bfloat16(v.w * r * wv.w);
}

// ---------------- rope apply (in place on fp32), GPT-NeoX half rotation -----
__global__ void rope_k(float* __restrict__ buf, const float* __restrict__ st,
                       const float* __restrict__ ct, int stride, int nheads) {
    int i = blockIdx.x * 256 + threadIdx.x;
    int per_row = 32 * nheads;
    int total = NTOK * per_row;
    if (i >= total) return;
    int row = i / per_row;
    int rem = i - row * per_row;
    int hh = rem >> 5;
    int d = rem & 31;
    int t = row & (TT - 1);
    float* p = buf + (size_t)row * stride + hh * 64;
    float x0 = p[d], x1 = p[d + 32];
    float c = ct[t * 64 + d], s = st[t * 64 + d];
    p[d] = x0 * c - x1 * s;
    p[d + 32] = x1 * c + x0 * s;
}

// ---------------- flash attention (fp32, causal, GQA h%4), bf16 out --------
// qkv layout per row (stride 1536): [q 16*64 | k 4*64 | v 4*64]
__global__ __launch_bounds__(256) void attn_k(const float* __restrict__ qkv,
                                              bf16* __restrict__ y) {
    int qt = blockIdx.x;  // query tile of 64
    int h = blockIdx.y;
    int b = blockIdx.z;
    int kvh = h & (KVHN - 1);

    __shared__ float Qs[64][65];
    __shared__ float Ks[32][65];
    __shared__ float Vs[32][65];
    __shared__ float Ss[64][33];

    int tid = threadIdx.x;
    for (int e = tid; e < 64 * 64; e += 256) {
        int r = e >> 6, d = e & 63;
        Qs[r][d] = qkv[(size_t)(b * TT + qt * 64 + r) * QKVD + h * 64 + d];
    }

    int r = tid >> 2;
    int g = (tid & 3) << 4;
    int jb = (tid & 3) << 3;

    float m = -INFINITY, l = 0.0f;
    float o[16];
#pragma unroll
    for (int i = 0; i < 16; i++) o[i] = 0.0f;

    int ktmax = 2 * qt + 1;
    for (int kt = 0; kt <= ktmax; ++kt) {
        __syncthreads();
        for (int e = tid; e < 32 * 64; e += 256) {
            int j = e >> 6, d = e & 63;
            size_t base = (size_t)(b * TT + kt * 32 + j) * QKVD + 1024;
            Ks[j][d] = qkv[base + kvh * 64 + d];
            Vs[j][d] = qkv[base + 256 + kvh * 64 + d];
        }
        __syncthreads();
        for (int jj = 0; jj < 8; jj++) {
            int j = jb + jj;
            float s = 0.0f;
#pragma unroll
            for (int d = 0; d < 64; d++) s += Qs[r][d] * Ks[j][d];
            s *= 0.125f;
            if (kt * 32 + j > qt * 64 + r) s = -INFINITY;
            Ss[r][j] = s;
        }
        __syncthreads();
        float mt = m;
#pragma unroll
        for (int j = 0; j < 32; j++) mt = fmaxf(mt, Ss[r][j]);
        float scale = expf(m - mt);
        float lsum = 0.0f;
#pragma unroll
        for (int i = 0; i < 16; i++) o[i] *= scale;
        for (int j = 0; j < 32; j++) {
            float p = expf(Ss[r][j] - mt);
            lsum += p;
#pragma unroll
            for (int i = 0; i < 16; i++) o[i] += p * Vs[j][g + i];
        }
        l = l * scale + lsum;
        m = mt;
    }
    float inv = 1.0f / l;
    size_t orow = (size_t)(b * TT + qt * 64 + r) * DD + h * 64 + g;
#pragma unroll
    for (int i = 0; i < 16; i++) y[orow + i] = __float2bfloat16(o[i] * inv);
}

// ---------------- silu(g)*u from fused gu (bf16) -> gb (bf16) --------------
__global__ void silu_mul_k(const bf16* __restrict__ gu, bf16* __restrict__ gb) {
    int i = blockIdx.x * 256 + threadIdx.x;
    if (i >= NTOK * IIP) return;
    int r = i / IIP, c = i - r * IIP;
    float gv = __bfloat162float(gu[(size_t)r * (2 * IIP) + c]);
    float uv = __bfloat162float(gu[(size_t)r * (2 * IIP) + IIP + c]);
    float s = gv / (1.0f + expf(-gv));
    gb[i] = __float2bfloat16(s * uv);
}

// ---------------- fp32 -> bf16 convert with row/col zero-padding -----------
__global__ void cvt_pad_k(const float* __restrict__ src, bf16* __restrict__ dst,
                          int Msrc, int Ksrc, int Kdst, int total) {
    for (int i = blockIdx.x * 256 + threadIdx.x; i < total; i += gridDim.x * 256) {
        int r = i / Kdst, c = i - r * Kdst;
        float v = (r < Msrc && c < Ksrc) ? src[(size_t)r * Ksrc + c] : 0.0f;
        dst[i] = __float2bfloat16(v);
    }
}

// ---------------- bf16 MFMA GEMM: C[N,M] = A[N,K] @ W[M,K]^T ----------------
// m97 structure: 128x128 tile, BK=32, 4 waves, 4x4 frags of 16x16x32, 2-barrier.
// MODE 0: C fp32; MODE 1: C fp32 += res; MODE 2: C bf16.
template <int MODE>
__global__ __launch_bounds__(256) void gemm_bt(const bf16* __restrict__ A,
                                               const bf16* __restrict__ W,
                                               const float* res, void* Cv,
                                               int N, int M, int K) {
    __shared__ __align__(16) bf16 As[128 * 32];
    __shared__ __align__(16) bf16 Bs[128 * 32];

    int t = threadIdx.x;
    int m0 = blockIdx.x * 128;
    int n0 = blockIdx.y * 128;
    int lane = t & 63;
    int wave = t >> 6;
    int wr = (wave >> 1) * 64;   // wave row origin in tile
    int wc = (wave & 1) * 64;    // wave col origin in tile

    // loader chunks: chunk c (0..511): row=c>>2, k8=(c&3)*8; thread does c=t, t+256
    int c1 = t, c2 = t + 256;
    const bf16* gA1 = A + (size_t)(n0 + (c1 >> 2)) * K + ((c1 & 3) * 8);
    const bf16* gA2 = A + (size_t)(n0 + (c2 >> 2)) * K + ((c2 & 3) * 8);
    const bf16* gB1 = W + (size_t)(m0 + (c1 >> 2)) * K + ((c1 & 3) * 8);
    const bf16* gB2 = W + (size_t)(m0 + (c2 >> 2)) * K + ((c2 & 3) * 8);

    f32x4 acc[4][4] = {};

    for (int k0 = 0; k0 < K; k0 += 32) {
        __syncthreads();
        GLOAD16(gA1 + k0, As + c1 * 8);
        GLOAD16(gA2 + k0, As + c2 * 8);
        GLOAD16(gB1 + k0, Bs + c1 * 8);
        GLOAD16(gB2 + k0, Bs + c2 * 8);
        __syncthreads();  // compiler drains vmcnt before barrier

        bf16x8 af[4], bfr[4];
#pragma unroll
        for (int m = 0; m < 4; m++)
            af[m] = *(const bf16x8*)(As + (wr + m * 16 + (lane & 15)) * 32 + (lane >> 4) * 8);
#pragma unroll
        for (int n = 0; n < 4; n++)
            bfr[n] = *(const bf16x8*)(Bs + (wc + n * 16 + (lane & 15)) * 32 + (lane >> 4) * 8);
#pragma unroll
        for (int m = 0; m < 4; m++)
#pragma unroll
            for (int n = 0; n < 4; n++)
                acc[m][n] = __builtin_amdgcn_mfma_f32_16x16x32_bf16(af[m], bfr[n], acc[m][n], 0, 0, 0);
    }

    // epilogue: C/D layout col=lane&15, row=(lane>>4)*4+reg
    float* Cf = (float*)Cv;
    bf16* Cb = (bf16*)Cv;
    int colb = m0 + wc + (lane & 15);
    int rowb = n0 + wr + (lane >> 4) * 4;
#pragma unroll
    for (int m = 0; m < 4; m++) {
#pragma unroll
        for (int n = 0; n < 4; n++) {
#pragma unroll
            for (int r = 0; r < 4; r++) {
                size_t off = (size_t)(rowb + m * 16 + r) * M + (colb + n * 16);
                float v = acc[m][n][r];
                if (MODE == 0) Cf[off] = v;
                if (MODE == 1) Cf[off] = v + res[off];
                if (MODE == 2) Cb[off] = __float2bfloat16(v);
            }
        }
    }
}

static inline int cvtgrid(int total) {
    int g = (total + 255) / 256;
    return g > 2048 ? 2048 : g;
}

extern "C" void kernel_launch(void* const* d_in, const int* in_sizes, int n_in,
                              void* d_out, int out_size, void* d_ws, size_t ws_size,
                              hipStream_t stream) {
    const int* idx    = (const int*)d_in[0];
    const float* wte  = (const float*)d_in[1];
    const float* Wq   = (const float*)d_in[2];
    const float* Wkv  = (const float*)d_in[3];
    const float* Wo   = (const float*)d_in[4];
    const float* Wg   = (const float*)d_in[5];
    const float* Wu   = (const float*)d_in[6];
    const float* Wd   = (const float*)d_in[7];
    const float* rms1 = (const float*)d_in[8];
    const float* rms2 = (const float*)d_in[9];
    const float* rmsf = (const float*)d_in[10];
    float* out = (float*)d_out;

    char* ws = (char*)d_ws;
    size_t off = 0;
    float* x = (float*)(ws + off);  off += (size_t)NTOK * DD * 4;
    bf16* xn = (bf16*)(ws + off);   off += (size_t)NTOK * DD * 2;
    float* st = (float*)(ws + off); off += (size_t)TT * 64 * 4;
    float* ct = (float*)(ws + off); off += (size_t)TT * 64 * 4;
    char* region = ws + off;
    size_t roff = 0;
    float* qkv = (float*)(region + roff);    roff += (size_t)NTOK * QKVD * 4;
    bf16* yb = (bf16*)(region + roff);       roff += (size_t)NTOK * DD * 2;
    bf16* gu = (bf16*)(region + roff);       roff += (size_t)NTOK * 2 * IIP * 2;
    bf16* gb = (bf16*)(region + roff);       roff += (size_t)NTOK * IIP * 2;
    bf16* Wqkv_buf = (bf16*)(region + roff); roff += (size_t)QKVD * DD * 2;
    bf16* Wo_buf = (bf16*)(region + roff);   roff += (size_t)DD * DD * 2;
    bf16* Wgu_buf = (bf16*)(region + roff);  roff += (size_t)2 * IIP * DD * 2;
    bf16* Wd_buf = (bf16*)(region + roff);   roff += (size_t)DD * IIP * 2;
    bf16* wte_bf = (bf16*)region;  // reuses whole region AFTER the layer loop

    rope_table_k<<<(TT * 64 + 255) / 256, 256, 0, stream>>>(st, ct);
    embed_k<<<NTOK, 256, 0, stream>>>(idx, wte, x);

    for (int l = 0; l < NL; ++l) {
        // --- attention block ---
        rmsnorm_k<<<NTOK, 256, 0, stream>>>(x, rms1 + (size_t)l * DD, xn);
        cvt_pad_k<<<cvtgrid(DD * DD), 256, 0, stream>>>(
            Wq + (size_t)l * DD * DD, Wqkv_buf, DD, DD, DD, DD * DD);
        cvt_pad_k<<<cvtgrid(512 * DD), 256, 0, stream>>>(
            Wkv + (size_t)l * 512 * DD, Wqkv_buf + (size_t)DD * DD, 512, DD, DD, 512 * DD);
        gemm_bt<0><<<dim3(QKVD / 128, NTOK / 128), 256, 0, stream>>>(
            xn, Wqkv_buf, nullptr, qkv, NTOK, QKVD, DD);
        rope_k<<<(NTOK * NH * 32 + 255) / 256, 256, 0, stream>>>(qkv, st, ct, QKVD, NH);
        rope_k<<<(NTOK * KVHN * 32 + 255) / 256, 256, 0, stream>>>(qkv + 1024, st, ct, QKVD, KVHN);
        attn_k<<<dim3(TT / 64, NH, BB), 256, 0, stream>>>(qkv, yb);
        cvt_pad_k<<<cvtgrid(DD * DD), 256, 0, stream>>>(
            Wo + (size_t)l * DD * DD, Wo_buf, DD, DD, DD, DD * DD);
        gemm_bt<1><<<dim3(DD / 128, NTOK / 128), 256, 0, stream>>>(
            yb, Wo_buf, x, x, NTOK, DD, DD);
        // --- mlp block ---
        rmsnorm_k<<<NTOK, 256, 0, stream>>>(x, rms2 + (size_t)l * DD, xn);
        cvt_pad_k<<<cvtgrid(IIP * DD), 256, 0, stream>>>(
            Wg + (size_t)l * II * DD, Wgu_buf, II, DD, DD, IIP * DD);
        cvt_pad_k<<<cvtgrid(IIP * DD), 256, 0, stream>>>(
            Wu + (size_t)l * II * DD, Wgu_buf + (size_t)IIP * DD, II, DD, DD, IIP * DD);
        gemm_bt<2><<<dim3(2 * IIP / 128, NTOK / 128), 256, 0, stream>>>(
            xn, Wgu_buf, nullptr, gu, NTOK, 2 * IIP, DD);
        silu_mul_k<<<(NTOK * IIP + 255) / 256, 256, 0, stream>>>(gu, gb);
        cvt_pad_k<<<cvtgrid(DD * IIP), 256, 0, stream>>>(
            Wd + (size_t)l * DD * II, Wd_buf, DD, II, IIP, DD * IIP);
        gemm_bt<1><<<dim3(DD / 128, NTOK / 128), 256, 0, stream>>>(
            gb, Wd_buf, x, x, NTOK, DD, IIP);
    }

    // --- final norm + tied lm_head ---
    rmsnorm_k<<<NTOK, 256, 0, stream>>>(x, rmsf, xn);
    cvt_pad_k<<<2048, 256, 0, stream>>>(wte, wte_bf, 32000, DD, DD, 32000 * DD);
    gemm_bt<0><<<dim3(32000 / 128, NTOK / 128), 256, 0, stream>>>(
        xn, wte_bf, nullptr, out, NTOK, 32000, DD);
}

// Round 3
// 1288.986 us; speedup vs baseline: 5.9463x; 3.0088x over previous
//
#include <hip/hip_runtime.h>
#include <hip/hip_bf16.h>
#include <math.h>

#define BB 2
#define TT 1024
#define DD 1024
#define NH 16
#define KVHN 4
#define NL 4
#define II 2730
#define IIP 2816          // padded intermediate (multiple of 128)
#define NTOK (BB * TT)
#define QKVD 1536         // fused q(1024)+kv(512) width
#define KSTR 72           // padded LDS row stride (bf16) for attention tiles

typedef __hip_bfloat16 bf16;
typedef __attribute__((ext_vector_type(8))) short bf16x8;
typedef __attribute__((ext_vector_type(4))) float f32x4;

#define GLOAD16(gp, lp)                                                        \
    __builtin_amdgcn_global_load_lds(                                          \
        (const __attribute__((address_space(1))) unsigned int*)(gp),           \
        (__attribute__((address_space(3))) unsigned int*)(lp), 16, 0, 0)

// ---------------- rope sin/cos table ----------------
__global__ void rope_table_k(float* __restrict__ st, float* __restrict__ ct) {
    int i = blockIdx.x * 256 + threadIdx.x;
    if (i >= TT * 64) return;
    int t = i >> 6, d = i & 63;
    float freq = powf(10000.0f, (float)(d & 31) / 32.0f);
    float ang = (float)t / freq;
    st[i] = sinf(ang);
    ct[i] = cosf(ang);
}

// ---------------- embedding gather (fp32 residual) ----------------
__global__ __launch_bounds__(256) void embed_k(const int* __restrict__ idx,
                                               const float* __restrict__ wte,
                                               float* __restrict__ x) {
    int row = blockIdx.x;
    int tok = idx[row];
    const float4* src = (const float4*)(wte + (size_t)tok * DD);
    float4* dst = (float4*)(x + (size_t)row * DD);
    dst[threadIdx.x] = src[threadIdx.x];
}

// ---------------- rmsnorm: fp32 in -> bf16 out ----------------
__global__ __launch_bounds__(256) void rmsnorm_k(const float* __restrict__ x,
                                                 const float* __restrict__ w,
                                                 bf16* __restrict__ o) {
    int row = blockIdx.x;
    float4 v = ((const float4*)(x + (size_t)row * DD))[threadIdx.x];
    float s = v.x * v.x + v.y * v.y + v.z * v.z + v.w * v.w;
#pragma unroll
    for (int off = 32; off > 0; off >>= 1) s += __shfl_down(s, off);
    __shared__ float red[4];
    if ((threadIdx.x & 63) == 0) red[threadIdx.x >> 6] = s;
    __syncthreads();
    float tot = red[0] + red[1] + red[2] + red[3];
    float r = rsqrtf(tot * (1.0f / DD) + 1e-6f);
    float4 wv = ((const float4*)w)[threadIdx.x];
    size_t base = (size_t)row * DD + threadIdx.x * 4;
    o[base + 0] = __float2bfloat16(v.x * r * wv.x);
    o[base + 1] = __float2bfloat16(v.y * r * wv.y);
    o[base + 2] = __float2bfloat16(v.z * r * wv.z);
    o[base + 3] = __float2bfloat16(v.w * r * wv.w);
}

// ---------------- pack q/k with rope (fp32 qkv -> bf16), q pre-scaled ------
__global__ void pack_qk_k(const float* __restrict__ qkv,
                          const float* __restrict__ st, const float* __restrict__ ct,
                          bf16* __restrict__ qp, bf16* __restrict__ kp) {
    int i = blockIdx.x * 256 + threadIdx.x;
    if (i >= NTOK * 20 * 32) return;
    int row = i / 640;
    int rem = i - row * 640;
    int slot = rem >> 5;
    int d = rem & 31;
    int b = row >> 10;
    int t = row & (TT - 1);
    int off = (slot < 16) ? slot * 64 : 1024 + (slot - 16) * 64;
    const float* p = qkv + (size_t)row * QKVD + off;
    float x0 = p[d], x1 = p[d + 32];
    float c = ct[t * 64 + d], s = st[t * 64 + d];
    float o0 = x0 * c - x1 * s;
    float o1 = x1 * c + x0 * s;
    if (slot < 16) {
        o0 *= 0.125f; o1 *= 0.125f;  // 1/sqrt(64) folded into q
        bf16* q = qp + (((size_t)(b * NH + slot) * TT + t) * 64);
        q[d] = __float2bfloat16(o0);
        q[d + 32] = __float2bfloat16(o1);
    } else {
        bf16* k = kp + (((size_t)(b * KVHN + (slot - 16)) * TT + t) * 64);
        k[d] = __float2bfloat16(o0);
        k[d + 32] = __float2bfloat16(o1);
    }
}

// ---------------- pack v transposed: qkv v-cols -> vt[b][kvh][64][T] -------
__global__ __launch_bounds__(256) void pack_v_k(const float* __restrict__ qkv,
                                                bf16* __restrict__ vt) {
    int t0 = blockIdx.x * 64;
    int kvh = blockIdx.y;
    int b = blockIdx.z;
    __shared__ float Ls[64][65];
    int tid = threadIdx.x;
    for (int e = tid; e < 64 * 64; e += 256) {
        int tl = e >> 6, d = e & 63;
        Ls[tl][d] = qkv[((size_t)(b * TT + t0 + tl)) * QKVD + 1280 + kvh * 64 + d];
    }
    __syncthreads();
    for (int e = tid; e < 64 * 64; e += 256) {
        int d = e >> 6, tl = e & 63;
        vt[((size_t)(b * KVHN + kvh) * 64 + d) * TT + t0 + tl] = __float2bfloat16(Ls[tl][d]);
    }
}

// ---------------- MFMA flash attention (bf16, causal, GQA h%4) ------------
// Block: (qt, h, b); 4 waves x 16 q-rows; KV tiles of 64.
__global__ __launch_bounds__(256) void attn_mfma_k(const bf16* __restrict__ qp,
                                                   const bf16* __restrict__ kp,
                                                   const bf16* __restrict__ vt,
                                                   bf16* __restrict__ y) {
    int qt = blockIdx.x;
    int h = blockIdx.y;
    int b = blockIdx.z;
    int kvh = h & (KVHN - 1);

    __shared__ __align__(16) bf16 Ks[64][KSTR];
    __shared__ __align__(16) bf16 Vt[64][KSTR];       // [d][k]
    __shared__ __align__(16) bf16 Ps[4][16][KSTR];    // per-wave P[q][k]

    int tid = threadIdx.x;
    int lane = tid & 63;
    int w = tid >> 6;
    int qi = lane & 15;
    int g = lane >> 4;

    // Q fragments (16 rows per wave), pre-scaled by 0.125
    const bf16* qbase = qp + (((size_t)(b * NH + h) * TT + qt * 64 + w * 16 + qi) * 64);
    bf16x8 qf0 = *(const bf16x8*)(qbase + g * 8);
    bf16x8 qf1 = *(const bf16x8*)(qbase + 32 + g * 8);

    const bf16* kg = kp + ((size_t)(b * KVHN + kvh) * TT) * 64;
    const bf16* vg = vt + ((size_t)(b * KVHN + kvh) * 64) * TT;

    f32x4 oacc[4] = {};
    float m = -INFINITY, l = 0.0f;
    int qglob = qt * 64 + w * 16 + qi;

    for (int kt = 0; kt <= qt; ++kt) {
        __syncthreads();
        {   // stage K tile [64][64] and Vt tile [64][64] (reg-staged, padded rows)
            int c0 = tid, c1 = tid + 256;
            *(bf16x8*)(&Ks[c0 >> 3][(c0 & 7) * 8]) =
                *(const bf16x8*)(kg + (size_t)(kt * 64 + (c0 >> 3)) * 64 + (c0 & 7) * 8);
            *(bf16x8*)(&Ks[c1 >> 3][(c1 & 7) * 8]) =
                *(const bf16x8*)(kg + (size_t)(kt * 64 + (c1 >> 3)) * 64 + (c1 & 7) * 8);
            *(bf16x8*)(&Vt[c0 >> 3][(c0 & 7) * 8]) =
                *(const bf16x8*)(vg + (size_t)(c0 >> 3) * TT + kt * 64 + (c0 & 7) * 8);
            *(bf16x8*)(&Vt[c1 >> 3][(c1 & 7) * 8]) =
                *(const bf16x8*)(vg + (size_t)(c1 >> 3) * TT + kt * 64 + (c1 & 7) * 8);
        }
        __syncthreads();

        // S^T = mfma(K, Q): lane holds S[k=st*16+g*4+r][q=qi]
        f32x4 sacc[4] = {};
#pragma unroll
        for (int stt = 0; stt < 4; ++stt) {
            bf16x8 kf0 = *(const bf16x8*)(&Ks[stt * 16 + qi][g * 8]);
            bf16x8 kf1 = *(const bf16x8*)(&Ks[stt * 16 + qi][32 + g * 8]);
            sacc[stt] = __builtin_amdgcn_mfma_f32_16x16x32_bf16(kf0, qf0, sacc[stt], 0, 0, 0);
            sacc[stt] = __builtin_amdgcn_mfma_f32_16x16x32_bf16(kf1, qf1, sacc[stt], 0, 0, 0);
        }

        if (kt == qt) {  // diagonal tile: causal mask
#pragma unroll
            for (int stt = 0; stt < 4; ++stt)
#pragma unroll
                for (int r = 0; r < 4; ++r) {
                    int kgl = kt * 64 + stt * 16 + g * 4 + r;
                    if (kgl > qglob) sacc[stt][r] = -INFINITY;
                }
        }

        // online softmax for q=qi (k-axis: 16 in-register + groups via xor 16,32)
        float tmax = -INFINITY;
#pragma unroll
        for (int stt = 0; stt < 4; ++stt)
#pragma unroll
            for (int r = 0; r < 4; ++r) tmax = fmaxf(tmax, sacc[stt][r]);
        tmax = fmaxf(tmax, __shfl_xor(tmax, 16));
        tmax = fmaxf(tmax, __shfl_xor(tmax, 32));
        float mnew = fmaxf(m, tmax);
        float scale = __expf(m - mnew);
        float psum = 0.0f;
#pragma unroll
        for (int stt = 0; stt < 4; ++stt) {
            bf16 pb[4];
#pragma unroll
            for (int r = 0; r < 4; ++r) {
                float p = __expf(sacc[stt][r] - mnew);
                psum += p;
                pb[r] = __float2bfloat16(p);
            }
            *(uint2*)(&Ps[w][qi][stt * 16 + g * 4]) = *(uint2*)pb;
        }
        psum += __shfl_xor(psum, 16);
        psum += __shfl_xor(psum, 32);
        l = l * scale + psum;
        m = mnew;

        // rescale O (rows q=g*4+r): broadcast per-row scale from lane qi=row
        float sc0 = __shfl(scale, g * 4 + 0);
        float sc1 = __shfl(scale, g * 4 + 1);
        float sc2 = __shfl(scale, g * 4 + 2);
        float sc3 = __shfl(scale, g * 4 + 3);
#pragma unroll
        for (int dt = 0; dt < 4; ++dt) {
            oacc[dt][0] *= sc0; oacc[dt][1] *= sc1;
            oacc[dt][2] *= sc2; oacc[dt][3] *= sc3;
        }

        // PV: O[q][d] += P[q][k] * Vt[d][k]
#pragma unroll
        for (int kc = 0; kc < 2; ++kc) {
            bf16x8 pa = *(const bf16x8*)(&Ps[w][qi][kc * 32 + g * 8]);
#pragma unroll
            for (int dt = 0; dt < 4; ++dt) {
                bf16x8 vb = *(const bf16x8*)(&Vt[dt * 16 + qi][kc * 32 + g * 8]);
                oacc[dt] = __builtin_amdgcn_mfma_f32_16x16x32_bf16(pa, vb, oacc[dt], 0, 0, 0);
            }
        }
    }

    // epilogue: divide by l, write y[q][h*64+d]
    float linv = 1.0f / l;
    float li0 = __shfl(linv, g * 4 + 0);
    float li1 = __shfl(linv, g * 4 + 1);
    float li2 = __shfl(linv, g * 4 + 2);
    float li3 = __shfl(linv, g * 4 + 3);
#pragma unroll
    for (int dt = 0; dt < 4; ++dt) {
        int dcol = h * 64 + dt * 16 + qi;
        size_t r0 = (size_t)(b * TT + qt * 64 + w * 16 + g * 4) * DD + dcol;
        y[r0 + 0 * DD] = __float2bfloat16(oacc[dt][0] * li0);
        y[r0 + 1 * DD] = __float2bfloat16(oacc[dt][1] * li1);
        y[r0 + 2 * DD] = __float2bfloat16(oacc[dt][2] * li2);
        y[r0 + 3 * DD] = __float2bfloat16(oacc[dt][3] * li3);
    }
}

// ---------------- silu(g)*u from fused gu (bf16) -> gb (bf16) --------------
__global__ void silu_mul_k(const bf16* __restrict__ gu, bf16* __restrict__ gb) {
    int i = blockIdx.x * 256 + threadIdx.x;
    if (i >= NTOK * IIP) return;
    int r = i / IIP, c = i - r * IIP;
    float gv = __bfloat162float(gu[(size_t)r * (2 * IIP) + c]);
    float uv = __bfloat162float(gu[(size_t)r * (2 * IIP) + IIP + c]);
    float s = gv / (1.0f + expf(-gv));
    gb[i] = __float2bfloat16(s * uv);
}

// ---------------- fp32 -> bf16 convert with row/col zero-padding -----------
__global__ void cvt_pad_k(const float* __restrict__ src, bf16* __restrict__ dst,
                          int Msrc, int Ksrc, int Kdst, int total) {
    for (int i = blockIdx.x * 256 + threadIdx.x; i < total; i += gridDim.x * 256) {
        int r = i / Kdst, c = i - r * Kdst;
        float v = (r < Msrc && c < Ksrc) ? src[(size_t)r * Ksrc + c] : 0.0f;
        dst[i] = __float2bfloat16(v);
    }
}

// ---------------- bf16 MFMA GEMM: C[N,M] = A[N,K] @ W[M,K]^T ----------------
// m97 structure: 128x128 tile, BK=32, 4 waves, 4x4 frags of 16x16x32.
// MODE 0: C fp32; MODE 1: C fp32 += res; MODE 2: C bf16.
template <int MODE>
__global__ __launch_bounds__(256) void gemm_bt(const bf16* __restrict__ A,
                                               const bf16* __restrict__ W,
                                               const float* res, void* Cv,
                                               int N, int M, int K) {
    __shared__ __align__(16) bf16 As[128 * 32];
    __shared__ __align__(16) bf16 Bs[128 * 32];

    int t = threadIdx.x;
    int m0 = blockIdx.x * 128;
    int n0 = blockIdx.y * 128;
    int lane = t & 63;
    int wave = t >> 6;
    int wr = (wave >> 1) * 64;
    int wc = (wave & 1) * 64;

    int c1 = t, c2 = t + 256;
    const bf16* gA1 = A + (size_t)(n0 + (c1 >> 2)) * K + ((c1 & 3) * 8);
    const bf16* gA2 = A + (size_t)(n0 + (c2 >> 2)) * K + ((c2 & 3) * 8);
    const bf16* gB1 = W + (size_t)(m0 + (c1 >> 2)) * K + ((c1 & 3) * 8);
    const bf16* gB2 = W + (size_t)(m0 + (c2 >> 2)) * K + ((c2 & 3) * 8);

    f32x4 acc[4][4] = {};

    for (int k0 = 0; k0 < K; k0 += 32) {
        __syncthreads();
        GLOAD16(gA1 + k0, As + c1 * 8);
        GLOAD16(gA2 + k0, As + c2 * 8);
        GLOAD16(gB1 + k0, Bs + c1 * 8);
        GLOAD16(gB2 + k0, Bs + c2 * 8);
        __syncthreads();

        bf16x8 af[4], bfr[4];
#pragma unroll
        for (int m = 0; m < 4; m++)
            af[m] = *(const bf16x8*)(As + (wr + m * 16 + (lane & 15)) * 32 + (lane >> 4) * 8);
#pragma unroll
        for (int n = 0; n < 4; n++)
            bfr[n] = *(const bf16x8*)(Bs + (wc + n * 16 + (lane & 15)) * 32 + (lane >> 4) * 8);
#pragma unroll
        for (int m = 0; m < 4; m++)
#pragma unroll
            for (int n = 0; n < 4; n++)
                acc[m][n] = __builtin_amdgcn_mfma_f32_16x16x32_bf16(af[m], bfr[n], acc[m][n], 0, 0, 0);
    }

    float* Cf = (float*)Cv;
    bf16* Cb = (bf16*)Cv;
    int colb = m0 + wc + (lane & 15);
    int rowb = n0 + wr + (lane >> 4) * 4;
#pragma unroll
    for (int m = 0; m < 4; m++) {
#pragma unroll
        for (int n = 0; n < 4; n++) {
#pragma unroll
            for (int r = 0; r < 4; r++) {
                size_t off = (size_t)(rowb + m * 16 + r) * M + (colb + n * 16);
                float v = acc[m][n][r];
                if (MODE == 0) Cf[off] = v;
                if (MODE == 1) Cf[off] = v + res[off];
                if (MODE == 2) Cb[off] = __float2bfloat16(v);
            }
        }
    }
}

static inline int cvtgrid(int total) {
    int g = (total + 255) / 256;
    return g > 2048 ? 2048 : g;
}

extern "C" void kernel_launch(void* const* d_in, const int* in_sizes, int n_in,
                              void* d_out, int out_size, void* d_ws, size_t ws_size,
                              hipStream_t stream) {
    const int* idx    = (const int*)d_in[0];
    const float* wte  = (const float*)d_in[1];
    const float* Wq   = (const float*)d_in[2];
    const float* Wkv  = (const float*)d_in[3];
    const float* Wo   = (const float*)d_in[4];
    const float* Wg   = (const float*)d_in[5];
    const float* Wu   = (const float*)d_in[6];
    const float* Wd   = (const float*)d_in[7];
    const float* rms1 = (const float*)d_in[8];
    const float* rms2 = (const float*)d_in[9];
    const float* rmsf = (const float*)d_in[10];
    float* out = (float*)d_out;

    char* ws = (char*)d_ws;
    size_t off = 0;
    float* x = (float*)(ws + off);  off += (size_t)NTOK * DD * 4;
    bf16* xn = (bf16*)(ws + off);   off += (size_t)NTOK * DD * 2;
    float* st = (float*)(ws + off); off += (size_t)TT * 64 * 4;
    float* ct = (float*)(ws + off); off += (size_t)TT * 64 * 4;
    char* region = ws + off;
    size_t roff = 0;
    float* qkv = (float*)(region + roff);    roff += (size_t)NTOK * QKVD * 4;
    bf16* yb = (bf16*)(region + roff);       roff += (size_t)NTOK * DD * 2;
    bf16* gu = (bf16*)(region + roff);       roff += (size_t)NTOK * 2 * IIP * 2;
    bf16* gb = (bf16*)(region + roff);       roff += (size_t)NTOK * IIP * 2;
    bf16* Wqkv_buf = (bf16*)(region + roff); roff += (size_t)QKVD * DD * 2;
    bf16* Wo_buf = (bf16*)(region + roff);   roff += (size_t)DD * DD * 2;
    bf16* Wgu_buf = (bf16*)(region + roff);  roff += (size_t)2 * IIP * DD * 2;
    bf16* Wd_buf = (bf16*)(region + roff);   roff += (size_t)DD * IIP * 2;
    // q/k/v packed buffers alias gu (gu only live between its GEMM and silu,
    // after attention of the same layer; qp/kp/vt dead by then)
    bf16* qp = gu;                                    // NTOK*1024
    bf16* kp = qp + (size_t)NTOK * DD;                // NTOK*256
    bf16* vt = kp + (size_t)BB * KVHN * TT * 64;      // NTOK*256
    bf16* wte_bf = (bf16*)region;  // reuses whole region AFTER the layer loop

    rope_table_k<<<(TT * 64 + 255) / 256, 256, 0, stream>>>(st, ct);
    embed_k<<<NTOK, 256, 0, stream>>>(idx, wte, x);

    for (int l = 0; l < NL; ++l) {
        // --- attention block ---
        rmsnorm_k<<<NTOK, 256, 0, stream>>>(x, rms1 + (size_t)l * DD, xn);
        cvt_pad_k<<<cvtgrid(DD * DD), 256, 0, stream>>>(
            Wq + (size_t)l * DD * DD, Wqkv_buf, DD, DD, DD, DD * DD);
        cvt_pad_k<<<cvtgrid(512 * DD), 256, 0, stream>>>(
            Wkv + (size_t)l * 512 * DD, Wqkv_buf + (size_t)DD * DD, 512, DD, DD, 512 * DD);
        gemm_bt<0><<<dim3(QKVD / 128, NTOK / 128), 256, 0, stream>>>(
            xn, Wqkv_buf, nullptr, qkv, NTOK, QKVD, DD);
        pack_qk_k<<<(NTOK * 20 * 32 + 255) / 256, 256, 0, stream>>>(qkv, st, ct, qp, kp);
        pack_v_k<<<dim3(TT / 64, KVHN, BB), 256, 0, stream>>>(qkv, vt);
        attn_mfma_k<<<dim3(TT / 64, NH, BB), 256, 0, stream>>>(qp, kp, vt, yb);
        cvt_pad_k<<<cvtgrid(DD * DD), 256, 0, stream>>>(
            Wo + (size_t)l * DD * DD, Wo_buf, DD, DD, DD, DD * DD);
        gemm_bt<1><<<dim3(DD / 128, NTOK / 128), 256, 0, stream>>>(
            yb, Wo_buf, x, x, NTOK, DD, DD);
        // --- mlp block ---
        rmsnorm_k<<<NTOK, 256, 0, stream>>>(x, rms2 + (size_t)l * DD, xn);
        cvt_pad_k<<<cvtgrid(IIP * DD), 256, 0, stream>>>(
            Wg + (size_t)l * II * DD, Wgu_buf, II, DD, DD, IIP * DD);
        cvt_pad_k<<<cvtgrid(IIP * DD), 256, 0, stream>>>(
            Wu + (size_t)l * II * DD, Wgu_buf + (size_t)IIP * DD, II, DD, DD, IIP * DD);
        gemm_bt<2><<<dim3(2 * IIP / 128, NTOK / 128), 256, 0, stream>>>(
            xn, Wgu_buf, nullptr, gu, NTOK, 2 * IIP, DD);
        silu_mul_k<<<(NTOK * IIP + 255) / 256, 256, 0, stream>>>(gu, gb);
        cvt_pad_k<<<cvtgrid(DD * IIP), 256, 0, stream>>>(
            Wd + (size_t)l * DD * II, Wd_buf, DD, II, IIP, DD * IIP);
        gemm_bt<1><<<dim3(DD / 128, NTOK / 128), 256, 0, stream>>>(
            gb, Wd_buf, x, x, NTOK, DD, IIP);
    }

    // --- final norm + tied lm_head ---
    rmsnorm_k<<<NTOK, 256, 0, stream>>>(x, rmsf, xn);
    cvt_pad_k<<<2048, 256, 0, stream>>>(wte, wte_bf, 32000, DD, DD, 32000 * DD);
    gemm_bt<0><<<dim3(32000 / 128, NTOK / 128), 256, 0, stream>>>(
        xn, wte_bf, nullptr, out, NTOK, 32000, DD);
}

// Round 4
// 1233.612 us; speedup vs baseline: 6.2132x; 1.0449x over previous
//
#include <hip/hip_runtime.h>
#include <hip/hip_bf16.h>
#include <math.h>

#define BB 2
#define TT 1024
#define DD 1024
#define NH 16
#define KVHN 4
#define NL 4
#define II 2730
#define IIP 2816          // padded intermediate (multiple of 128)
#define NTOK (BB * TT)
#define QKVD 1536         // fused q(1024)+kv(512) width
#define KSTR 72           // padded LDS row stride (bf16) for attention tiles

typedef __hip_bfloat16 bf16;
typedef __attribute__((ext_vector_type(8))) short bf16x8;
typedef __attribute__((ext_vector_type(4))) float f32x4;

#define GLOAD16(gp, lp)                                                        \
    __builtin_amdgcn_global_load_lds(                                          \
        (const __attribute__((address_space(1))) unsigned int*)(gp),           \
        (__attribute__((address_space(3))) unsigned int*)(lp), 16, 0, 0)

__device__ inline float b2f(unsigned short u) {
    union { unsigned int i; float f; } v;
    v.i = (unsigned int)u << 16;
    return v.f;
}
__device__ inline unsigned short f2b(float f) {
    union { float f; unsigned int i; } v;
    __hip_bfloat16 b = __float2bfloat16(f);
    return *(unsigned short*)&b;
}

// ---------------- rope sin/cos table ----------------
__global__ void rope_table_k(float* __restrict__ st, float* __restrict__ ct) {
    int i = blockIdx.x * 256 + threadIdx.x;
    if (i >= TT * 64) return;
    int t = i >> 6, d = i & 63;
    float freq = powf(10000.0f, (float)(d & 31) / 32.0f);
    float ang = (float)t / freq;
    st[i] = sinf(ang);
    ct[i] = cosf(ang);
}

// ---------------- embedding gather (fp32 residual) ----------------
__global__ __launch_bounds__(256) void embed_k(const int* __restrict__ idx,
                                               const float* __restrict__ wte,
                                               float* __restrict__ x) {
    int row = blockIdx.x;
    int tok = idx[row];
    const float4* src = (const float4*)(wte + (size_t)tok * DD);
    float4* dst = (float4*)(x + (size_t)row * DD);
    dst[threadIdx.x] = src[threadIdx.x];
}

// ---------------- rmsnorm: fp32 in -> bf16 out ----------------
__global__ __launch_bounds__(256) void rmsnorm_k(const float* __restrict__ x,
                                                 const float* __restrict__ w,
                                                 bf16* __restrict__ o) {
    int row = blockIdx.x;
    float4 v = ((const float4*)(x + (size_t)row * DD))[threadIdx.x];
    float s = v.x * v.x + v.y * v.y + v.z * v.z + v.w * v.w;
#pragma unroll
    for (int off = 32; off > 0; off >>= 1) s += __shfl_down(s, off);
    __shared__ float red[4];
    if ((threadIdx.x & 63) == 0) red[threadIdx.x >> 6] = s;
    __syncthreads();
    float tot = red[0] + red[1] + red[2] + red[3];
    float r = rsqrtf(tot * (1.0f / DD) + 1e-6f);
    float4 wv = ((const float4*)w)[threadIdx.x];
    size_t base = (size_t)row * DD + threadIdx.x * 4;
    ushort4 ov;
    ov.x = f2b(v.x * r * wv.x);
    ov.y = f2b(v.y * r * wv.y);
    ov.z = f2b(v.z * r * wv.z);
    ov.w = f2b(v.w * r * wv.w);
    *(ushort4*)(o + base) = ov;
}

// ---------------- pack q/k with rope (fp32 qkv -> bf16), q pre-scaled ------
__global__ void pack_qk_k(const float* __restrict__ qkv,
                          const float* __restrict__ st, const float* __restrict__ ct,
                          bf16* __restrict__ qp, bf16* __restrict__ kp) {
    int i = blockIdx.x * 256 + threadIdx.x;
    if (i >= NTOK * 20 * 32) return;
    int row = i / 640;
    int rem = i - row * 640;
    int slot = rem >> 5;
    int d = rem & 31;
    int b = row >> 10;
    int t = row & (TT - 1);
    int off = (slot < 16) ? slot * 64 : 1024 + (slot - 16) * 64;
    const float* p = qkv + (size_t)row * QKVD + off;
    float x0 = p[d], x1 = p[d + 32];
    float c = ct[t * 64 + d], s = st[t * 64 + d];
    float o0 = x0 * c - x1 * s;
    float o1 = x1 * c + x0 * s;
    if (slot < 16) {
        o0 *= 0.125f; o1 *= 0.125f;  // 1/sqrt(64) folded into q
        bf16* q = qp + (((size_t)(b * NH + slot) * TT + t) * 64);
        q[d] = __float2bfloat16(o0);
        q[d + 32] = __float2bfloat16(o1);
    } else {
        bf16* k = kp + (((size_t)(b * KVHN + (slot - 16)) * TT + t) * 64);
        k[d] = __float2bfloat16(o0);
        k[d + 32] = __float2bfloat16(o1);
    }
}

// ---------------- pack v transposed: qkv v-cols -> vt[b][kvh][64][T] -------
__global__ __launch_bounds__(256) void pack_v_k(const float* __restrict__ qkv,
                                                bf16* __restrict__ vt) {
    int t0 = blockIdx.x * 64;
    int kvh = blockIdx.y;
    int b = blockIdx.z;
    __shared__ float Ls[64][65];
    int tid = threadIdx.x;
    for (int e = tid; e < 64 * 64; e += 256) {
        int tl = e >> 6, d = e & 63;
        Ls[tl][d] = qkv[((size_t)(b * TT + t0 + tl)) * QKVD + 1280 + kvh * 64 + d];
    }
    __syncthreads();
    for (int e = tid; e < 64 * 64; e += 256) {
        int d = e >> 6, tl = e & 63;
        vt[((size_t)(b * KVHN + kvh) * 64 + d) * TT + t0 + tl] = __float2bfloat16(Ls[tl][d]);
    }
}

// ---------------- MFMA flash attention (bf16, causal, GQA h%4) ------------
__global__ __launch_bounds__(256) void attn_mfma_k(const bf16* __restrict__ qp,
                                                   const bf16* __restrict__ kp,
                                                   const bf16* __restrict__ vt,
                                                   bf16* __restrict__ y) {
    int qt = blockIdx.x;
    int h = blockIdx.y;
    int b = blockIdx.z;
    int kvh = h & (KVHN - 1);

    __shared__ __align__(16) bf16 Ks[64][KSTR];
    __shared__ __align__(16) bf16 Vt[64][KSTR];       // [d][k]
    __shared__ __align__(16) bf16 Ps[4][16][KSTR];    // per-wave P[q][k]

    int tid = threadIdx.x;
    int lane = tid & 63;
    int w = tid >> 6;
    int qi = lane & 15;
    int g = lane >> 4;

    const bf16* qbase = qp + (((size_t)(b * NH + h) * TT + qt * 64 + w * 16 + qi) * 64);
    bf16x8 qf0 = *(const bf16x8*)(qbase + g * 8);
    bf16x8 qf1 = *(const bf16x8*)(qbase + 32 + g * 8);

    const bf16* kg = kp + ((size_t)(b * KVHN + kvh) * TT) * 64;
    const bf16* vg = vt + ((size_t)(b * KVHN + kvh) * 64) * TT;

    f32x4 oacc[4] = {};
    float m = -INFINITY, l = 0.0f;
    int qglob = qt * 64 + w * 16 + qi;

    for (int kt = 0; kt <= qt; ++kt) {
        __syncthreads();
        {
            int c0 = tid, c1 = tid + 256;
            *(bf16x8*)(&Ks[c0 >> 3][(c0 & 7) * 8]) =
                *(const bf16x8*)(kg + (size_t)(kt * 64 + (c0 >> 3)) * 64 + (c0 & 7) * 8);
            *(bf16x8*)(&Ks[c1 >> 3][(c1 & 7) * 8]) =
                *(const bf16x8*)(kg + (size_t)(kt * 64 + (c1 >> 3)) * 64 + (c1 & 7) * 8);
            *(bf16x8*)(&Vt[c0 >> 3][(c0 & 7) * 8]) =
                *(const bf16x8*)(vg + (size_t)(c0 >> 3) * TT + kt * 64 + (c0 & 7) * 8);
            *(bf16x8*)(&Vt[c1 >> 3][(c1 & 7) * 8]) =
                *(const bf16x8*)(vg + (size_t)(c1 >> 3) * TT + kt * 64 + (c1 & 7) * 8);
        }
        __syncthreads();

        f32x4 sacc[4] = {};
#pragma unroll
        for (int stt = 0; stt < 4; ++stt) {
            bf16x8 kf0 = *(const bf16x8*)(&Ks[stt * 16 + qi][g * 8]);
            bf16x8 kf1 = *(const bf16x8*)(&Ks[stt * 16 + qi][32 + g * 8]);
            sacc[stt] = __builtin_amdgcn_mfma_f32_16x16x32_bf16(kf0, qf0, sacc[stt], 0, 0, 0);
            sacc[stt] = __builtin_amdgcn_mfma_f32_16x16x32_bf16(kf1, qf1, sacc[stt], 0, 0, 0);
        }

        if (kt == qt) {
#pragma unroll
            for (int stt = 0; stt < 4; ++stt)
#pragma unroll
                for (int r = 0; r < 4; ++r) {
                    int kgl = kt * 64 + stt * 16 + g * 4 + r;
                    if (kgl > qglob) sacc[stt][r] = -INFINITY;
                }
        }

        float tmax = -INFINITY;
#pragma unroll
        for (int stt = 0; stt < 4; ++stt)
#pragma unroll
            for (int r = 0; r < 4; ++r) tmax = fmaxf(tmax, sacc[stt][r]);
        tmax = fmaxf(tmax, __shfl_xor(tmax, 16));
        tmax = fmaxf(tmax, __shfl_xor(tmax, 32));
        float mnew = fmaxf(m, tmax);
        float scale = __expf(m - mnew);
        float psum = 0.0f;
#pragma unroll
        for (int stt = 0; stt < 4; ++stt) {
            bf16 pb[4];
#pragma unroll
            for (int r = 0; r < 4; ++r) {
                float p = __expf(sacc[stt][r] - mnew);
                psum += p;
                pb[r] = __float2bfloat16(p);
            }
            *(uint2*)(&Ps[w][qi][stt * 16 + g * 4]) = *(uint2*)pb;
        }
        psum += __shfl_xor(psum, 16);
        psum += __shfl_xor(psum, 32);
        l = l * scale + psum;
        m = mnew;

        float sc0 = __shfl(scale, g * 4 + 0);
        float sc1 = __shfl(scale, g * 4 + 1);
        float sc2 = __shfl(scale, g * 4 + 2);
        float sc3 = __shfl(scale, g * 4 + 3);
#pragma unroll
        for (int dt = 0; dt < 4; ++dt) {
            oacc[dt][0] *= sc0; oacc[dt][1] *= sc1;
            oacc[dt][2] *= sc2; oacc[dt][3] *= sc3;
        }

#pragma unroll
        for (int kc = 0; kc < 2; ++kc) {
            bf16x8 pa = *(const bf16x8*)(&Ps[w][qi][kc * 32 + g * 8]);
#pragma unroll
            for (int dt = 0; dt < 4; ++dt) {
                bf16x8 vb = *(const bf16x8*)(&Vt[dt * 16 + qi][kc * 32 + g * 8]);
                oacc[dt] = __builtin_amdgcn_mfma_f32_16x16x32_bf16(pa, vb, oacc[dt], 0, 0, 0);
            }
        }
    }

    float linv = 1.0f / l;
    float li0 = __shfl(linv, g * 4 + 0);
    float li1 = __shfl(linv, g * 4 + 1);
    float li2 = __shfl(linv, g * 4 + 2);
    float li3 = __shfl(linv, g * 4 + 3);
#pragma unroll
    for (int dt = 0; dt < 4; ++dt) {
        int dcol = h * 64 + dt * 16 + qi;
        size_t r0 = (size_t)(b * TT + qt * 64 + w * 16 + g * 4) * DD + dcol;
        y[r0 + 0 * DD] = __float2bfloat16(oacc[dt][0] * li0);
        y[r0 + 1 * DD] = __float2bfloat16(oacc[dt][1] * li1);
        y[r0 + 2 * DD] = __float2bfloat16(oacc[dt][2] * li2);
        y[r0 + 3 * DD] = __float2bfloat16(oacc[dt][3] * li3);
    }
}

// ---------------- silu(g)*u from fused gu (bf16) -> gb (bf16), x4 vec ------
__global__ void silu_mul_k(const bf16* __restrict__ gu, bf16* __restrict__ gb) {
    int i4 = blockIdx.x * 256 + threadIdx.x;
    if (i4 >= NTOK * IIP / 4) return;
    int i = i4 * 4;
    int r = i / IIP, c = i - r * IIP;
    ushort4 gv = *(const ushort4*)(gu + (size_t)r * (2 * IIP) + c);
    ushort4 uv = *(const ushort4*)(gu + (size_t)r * (2 * IIP) + IIP + c);
    ushort4 o;
    {
        float g0 = b2f(gv.x); o.x = f2b(g0 / (1.0f + __expf(-g0)) * b2f(uv.x));
        float g1 = b2f(gv.y); o.y = f2b(g1 / (1.0f + __expf(-g1)) * b2f(uv.y));
        float g2 = b2f(gv.z); o.z = f2b(g2 / (1.0f + __expf(-g2)) * b2f(uv.z));
        float g3 = b2f(gv.w); o.w = f2b(g3 / (1.0f + __expf(-g3)) * b2f(uv.w));
    }
    *(ushort4*)(gb + i) = o;
}

// ---------------- fp32 -> bf16 convert with row/col zero-padding, x4 vec ---
__global__ void cvt_pad_k(const float* __restrict__ src, bf16* __restrict__ dst,
                          int Msrc, int Ksrc, int Kdst, int total4) {
    for (int i4 = blockIdx.x * 256 + threadIdx.x; i4 < total4; i4 += gridDim.x * 256) {
        int i = i4 * 4;
        int r = i / Kdst, c = i - r * Kdst;
        ushort4 o;
        if (r < Msrc && c + 4 <= Ksrc && (Ksrc & 3) == 0) {
            float4 v = *(const float4*)(src + (size_t)r * Ksrc + c);
            o.x = f2b(v.x); o.y = f2b(v.y); o.z = f2b(v.z); o.w = f2b(v.w);
        } else {
            float v0 = (r < Msrc && c + 0 < Ksrc) ? src[(size_t)r * Ksrc + c + 0] : 0.0f;
            float v1 = (r < Msrc && c + 1 < Ksrc) ? src[(size_t)r * Ksrc + c + 1] : 0.0f;
            float v2 = (r < Msrc && c + 2 < Ksrc) ? src[(size_t)r * Ksrc + c + 2] : 0.0f;
            float v3 = (r < Msrc && c + 3 < Ksrc) ? src[(size_t)r * Ksrc + c + 3] : 0.0f;
            o.x = f2b(v0); o.y = f2b(v1); o.z = f2b(v2); o.w = f2b(v3);
        }
        *(ushort4*)(dst + i) = o;
    }
}

// ---------------- bf16 MFMA GEMM: C[N,M] = A[N,K] @ W[M,K]^T ----------------
// m97 structure: 128x128 tile, BK=32, 4 waves, 4x4 frags of 16x16x32.
// 1D grid, n-fastest decode + bijective XCD-chunk swizzle (nwg % 8 == 0).
// MODE 0: C fp32; MODE 1: C fp32 += res; MODE 2: C bf16.
template <int MODE>
__global__ __launch_bounds__(256) void gemm_bt(const bf16* __restrict__ A,
                                               const bf16* __restrict__ W,
                                               const float* res, void* Cv,
                                               int N, int M, int K) {
    __shared__ __align__(16) bf16 As[128 * 32];
    __shared__ __align__(16) bf16 Bs[128 * 32];

    int t = threadIdx.x;
    int nnt = N >> 7;                 // n-tiles (fast axis)
    int nwg = (M >> 7) * nnt;
    int orig = blockIdx.x;
    int q8 = nwg >> 3;
    int wgid = (orig & 7) * q8 + (orig >> 3);   // XCD-chunked, bijective
    int mt = wgid / nnt;
    int nt = wgid - mt * nnt;
    int m0 = mt * 128;
    int n0 = nt * 128;

    int lane = t & 63;
    int wave = t >> 6;
    int wr = (wave >> 1) * 64;
    int wc = (wave & 1) * 64;

    int c1 = t, c2 = t + 256;
    const bf16* gA1 = A + (size_t)(n0 + (c1 >> 2)) * K + ((c1 & 3) * 8);
    const bf16* gA2 = A + (size_t)(n0 + (c2 >> 2)) * K + ((c2 & 3) * 8);
    const bf16* gB1 = W + (size_t)(m0 + (c1 >> 2)) * K + ((c1 & 3) * 8);
    const bf16* gB2 = W + (size_t)(m0 + (c2 >> 2)) * K + ((c2 & 3) * 8);

    f32x4 acc[4][4] = {};

    for (int k0 = 0; k0 < K; k0 += 32) {
        __syncthreads();
        GLOAD16(gA1 + k0, As + c1 * 8);
        GLOAD16(gA2 + k0, As + c2 * 8);
        GLOAD16(gB1 + k0, Bs + c1 * 8);
        GLOAD16(gB2 + k0, Bs + c2 * 8);
        __syncthreads();

        bf16x8 af[4], bfr[4];
#pragma unroll
        for (int m = 0; m < 4; m++)
            af[m] = *(const bf16x8*)(As + (wr + m * 16 + (lane & 15)) * 32 + (lane >> 4) * 8);
#pragma unroll
        for (int n = 0; n < 4; n++)
            bfr[n] = *(const bf16x8*)(Bs + (wc + n * 16 + (lane & 15)) * 32 + (lane >> 4) * 8);
#pragma unroll
        for (int m = 0; m < 4; m++)
#pragma unroll
            for (int n = 0; n < 4; n++)
                acc[m][n] = __builtin_amdgcn_mfma_f32_16x16x32_bf16(af[m], bfr[n], acc[m][n], 0, 0, 0);
    }

    float* Cf = (float*)Cv;
    bf16* Cb = (bf16*)Cv;
    int colb = m0 + wc + (lane & 15);
    int rowb = n0 + wr + (lane >> 4) * 4;
#pragma unroll
    for (int m = 0; m < 4; m++) {
#pragma unroll
        for (int n = 0; n < 4; n++) {
#pragma unroll
            for (int r = 0; r < 4; r++) {
                size_t off = (size_t)(rowb + m * 16 + r) * M + (colb + n * 16);
                float v = acc[m][n][r];
                if (MODE == 0) Cf[off] = v;
                if (MODE == 1) Cf[off] = v + res[off];
                if (MODE == 2) Cb[off] = __float2bfloat16(v);
            }
        }
    }
}

static inline int cvtgrid(int total) {
    int g = (total + 255) / 256;
    return g > 2048 ? 2048 : g;
}
#define GEMM_GRID(M_) (((M_) >> 7) * (NTOK >> 7))

extern "C" void kernel_launch(void* const* d_in, const int* in_sizes, int n_in,
                              void* d_out, int out_size, void* d_ws, size_t ws_size,
                              hipStream_t stream) {
    const int* idx    = (const int*)d_in[0];
    const float* wte  = (const float*)d_in[1];
    const float* Wq   = (const float*)d_in[2];
    const float* Wkv  = (const float*)d_in[3];
    const float* Wo   = (const float*)d_in[4];
    const float* Wg   = (const float*)d_in[5];
    const float* Wu   = (const float*)d_in[6];
    const float* Wd   = (const float*)d_in[7];
    const float* rms1 = (const float*)d_in[8];
    const float* rms2 = (const float*)d_in[9];
    const float* rmsf = (const float*)d_in[10];
    float* out = (float*)d_out;

    char* ws = (char*)d_ws;
    size_t off = 0;
    float* x = (float*)(ws + off);  off += (size_t)NTOK * DD * 4;
    bf16* xn = (bf16*)(ws + off);   off += (size_t)NTOK * DD * 2;
    float* st = (float*)(ws + off); off += (size_t)TT * 64 * 4;
    float* ct = (float*)(ws + off); off += (size_t)TT * 64 * 4;
    char* region = ws + off;
    size_t roff = 0;
    float* qkv = (float*)(region + roff);    roff += (size_t)NTOK * QKVD * 4;
    bf16* yb = (bf16*)(region + roff);       roff += (size_t)NTOK * DD * 2;
    bf16* gu = (bf16*)(region + roff);       roff += (size_t)NTOK * 2 * IIP * 2;
    bf16* gb = (bf16*)(region + roff);       roff += (size_t)NTOK * IIP * 2;
    bf16* Wqkv_buf = (bf16*)(region + roff); roff += (size_t)QKVD * DD * 2;
    bf16* Wo_buf = (bf16*)(region + roff);   roff += (size_t)DD * DD * 2;
    bf16* Wgu_buf = (bf16*)(region + roff);  roff += (size_t)2 * IIP * DD * 2;
    bf16* Wd_buf = (bf16*)(region + roff);   roff += (size_t)DD * IIP * 2;
    bf16* qp = gu;                                    // aliases (gu dead here)
    bf16* kp = qp + (size_t)NTOK * DD;
    bf16* vt = kp + (size_t)BB * KVHN * TT * 64;
    bf16* wte_bf = (bf16*)region;  // reuses whole region AFTER the layer loop

    rope_table_k<<<(TT * 64 + 255) / 256, 256, 0, stream>>>(st, ct);
    embed_k<<<NTOK, 256, 0, stream>>>(idx, wte, x);

    for (int l = 0; l < NL; ++l) {
        // --- attention block ---
        rmsnorm_k<<<NTOK, 256, 0, stream>>>(x, rms1 + (size_t)l * DD, xn);
        cvt_pad_k<<<cvtgrid(DD * DD / 4), 256, 0, stream>>>(
            Wq + (size_t)l * DD * DD, Wqkv_buf, DD, DD, DD, DD * DD / 4);
        cvt_pad_k<<<cvtgrid(512 * DD / 4), 256, 0, stream>>>(
            Wkv + (size_t)l * 512 * DD, Wqkv_buf + (size_t)DD * DD, 512, DD, DD, 512 * DD / 4);
        gemm_bt<0><<<GEMM_GRID(QKVD), 256, 0, stream>>>(
            xn, Wqkv_buf, nullptr, qkv, NTOK, QKVD, DD);
        pack_qk_k<<<(NTOK * 20 * 32 + 255) / 256, 256, 0, stream>>>(qkv, st, ct, qp, kp);
        pack_v_k<<<dim3(TT / 64, KVHN, BB), 256, 0, stream>>>(qkv, vt);
        attn_mfma_k<<<dim3(TT / 64, NH, BB), 256, 0, stream>>>(qp, kp, vt, yb);
        cvt_pad_k<<<cvtgrid(DD * DD / 4), 256, 0, stream>>>(
            Wo + (size_t)l * DD * DD, Wo_buf, DD, DD, DD, DD * DD / 4);
        gemm_bt<1><<<GEMM_GRID(DD), 256, 0, stream>>>(
            yb, Wo_buf, x, x, NTOK, DD, DD);
        // --- mlp block ---
        rmsnorm_k<<<NTOK, 256, 0, stream>>>(x, rms2 + (size_t)l * DD, xn);
        cvt_pad_k<<<cvtgrid(IIP * DD / 4), 256, 0, stream>>>(
            Wg + (size_t)l * II * DD, Wgu_buf, II, DD, DD, IIP * DD / 4);
        cvt_pad_k<<<cvtgrid(IIP * DD / 4), 256, 0, stream>>>(
            Wu + (size_t)l * II * DD, Wgu_buf + (size_t)IIP * DD, II, DD, DD, IIP * DD / 4);
        gemm_bt<2><<<GEMM_GRID(2 * IIP), 256, 0, stream>>>(
            xn, Wgu_buf, nullptr, gu, NTOK, 2 * IIP, DD);
        silu_mul_k<<<(NTOK * IIP / 4 + 255) / 256, 256, 0, stream>>>(gu, gb);
        cvt_pad_k<<<cvtgrid(DD * IIP / 4), 256, 0, stream>>>(
            Wd + (size_t)l * DD * II, Wd_buf, DD, II, IIP, DD * IIP / 4);
        gemm_bt<1><<<GEMM_GRID(DD), 256, 0, stream>>>(
            gb, Wd_buf, x, x, NTOK, DD, IIP);
    }

    // --- final norm + tied lm_head ---
    rmsnorm_k<<<NTOK, 256, 0, stream>>>(x, rmsf, xn);
    cvt_pad_k<<<2048, 256, 0, stream>>>(wte, wte_bf, 32000, DD, DD, 32000 * DD / 4);
    gemm_bt<0><<<GEMM_GRID(32000), 256, 0, stream>>>(
        xn, wte_bf, nullptr, out, NTOK, 32000, DD);
}

// Round 5
// 1070.911 us; speedup vs baseline: 7.1572x; 1.1519x over previous
//
#include <hip/hip_runtime.h>
#include <hip/hip_bf16.h>
#include <math.h>

#define BB 2
#define TT 1024
#define DD 1024
#define NH 16
#define KVHN 4
#define NL 4
#define II 2730
#define IIP 2816          // padded intermediate (multiple of 128)
#define NTOK (BB * TT)
#define QKVD 1536         // fused q(1024)+kv(512) width
#define KSTR 72           // padded LDS row stride (bf16) for attention tiles

typedef __hip_bfloat16 bf16;
typedef __attribute__((ext_vector_type(8))) short bf16x8;
typedef __attribute__((ext_vector_type(4))) float f32x4;

#define GLOAD16(gp, lp)                                                        \
    __builtin_amdgcn_global_load_lds(                                          \
        (const __attribute__((address_space(1))) unsigned int*)(gp),           \
        (__attribute__((address_space(3))) unsigned int*)(lp), 16, 0, 0)

__device__ inline float b2f(unsigned short u) {
    union { unsigned int i; float f; } v;
    v.i = (unsigned int)u << 16;
    return v.f;
}
__device__ inline unsigned short f2b(float f) {
    __hip_bfloat16 b = __float2bfloat16(f);
    return *(unsigned short*)&b;
}

// ---------------- rope sin/cos table ----------------
__global__ void rope_table_k(float* __restrict__ st, float* __restrict__ ct) {
    int i = blockIdx.x * 256 + threadIdx.x;
    if (i >= TT * 64) return;
    int t = i >> 6, d = i & 63;
    float freq = powf(10000.0f, (float)(d & 31) / 32.0f);
    float ang = (float)t / freq;
    st[i] = sinf(ang);
    ct[i] = cosf(ang);
}

// ---------------- embedding gather (fp32 residual) ----------------
__global__ __launch_bounds__(256) void embed_k(const int* __restrict__ idx,
                                               const float* __restrict__ wte,
                                               float* __restrict__ x) {
    int row = blockIdx.x;
    int tok = idx[row];
    const float4* src = (const float4*)(wte + (size_t)tok * DD);
    float4* dst = (float4*)(x + (size_t)row * DD);
    dst[threadIdx.x] = src[threadIdx.x];
}

// ---------------- rmsnorm: fp32 in -> bf16 out ----------------
__global__ __launch_bounds__(256) void rmsnorm_k(const float* __restrict__ x,
                                                 const float* __restrict__ w,
                                                 bf16* __restrict__ o) {
    int row = blockIdx.x;
    float4 v = ((const float4*)(x + (size_t)row * DD))[threadIdx.x];
    float s = v.x * v.x + v.y * v.y + v.z * v.z + v.w * v.w;
#pragma unroll
    for (int off = 32; off > 0; off >>= 1) s += __shfl_down(s, off);
    __shared__ float red[4];
    if ((threadIdx.x & 63) == 0) red[threadIdx.x >> 6] = s;
    __syncthreads();
    float tot = red[0] + red[1] + red[2] + red[3];
    float r = rsqrtf(tot * (1.0f / DD) + 1e-6f);
    float4 wv = ((const float4*)w)[threadIdx.x];
    size_t base = (size_t)row * DD + threadIdx.x * 4;
    ushort4 ov;
    ov.x = f2b(v.x * r * wv.x);
    ov.y = f2b(v.y * r * wv.y);
    ov.z = f2b(v.z * r * wv.z);
    ov.w = f2b(v.w * r * wv.w);
    *(ushort4*)(o + base) = ov;
}

// ---------------- pack q/k with rope (fp32 qkv -> bf16), q pre-scaled ------
__global__ void pack_qk_k(const float* __restrict__ qkv,
                          const float* __restrict__ st, const float* __restrict__ ct,
                          bf16* __restrict__ qp, bf16* __restrict__ kp) {
    int i = blockIdx.x * 256 + threadIdx.x;
    if (i >= NTOK * 20 * 32) return;
    int row = i / 640;
    int rem = i - row * 640;
    int slot = rem >> 5;
    int d = rem & 31;
    int b = row >> 10;
    int t = row & (TT - 1);
    int off = (slot < 16) ? slot * 64 : 1024 + (slot - 16) * 64;
    const float* p = qkv + (size_t)row * QKVD + off;
    float x0 = p[d], x1 = p[d + 32];
    float c = ct[t * 64 + d], s = st[t * 64 + d];
    float o0 = x0 * c - x1 * s;
    float o1 = x1 * c + x0 * s;
    if (slot < 16) {
        o0 *= 0.125f; o1 *= 0.125f;  // 1/sqrt(64) folded into q
        bf16* q = qp + (((size_t)(b * NH + slot) * TT + t) * 64);
        q[d] = __float2bfloat16(o0);
        q[d + 32] = __float2bfloat16(o1);
    } else {
        bf16* k = kp + (((size_t)(b * KVHN + (slot - 16)) * TT + t) * 64);
        k[d] = __float2bfloat16(o0);
        k[d + 32] = __float2bfloat16(o1);
    }
}

// ---------------- pack v transposed: qkv v-cols -> vt[b][kvh][64][T] -------
__global__ __launch_bounds__(256) void pack_v_k(const float* __restrict__ qkv,
                                                bf16* __restrict__ vt) {
    int t0 = blockIdx.x * 64;
    int kvh = blockIdx.y;
    int b = blockIdx.z;
    __shared__ float Ls[64][65];
    int tid = threadIdx.x;
    for (int e = tid; e < 64 * 64; e += 256) {
        int tl = e >> 6, d = e & 63;
        Ls[tl][d] = qkv[((size_t)(b * TT + t0 + tl)) * QKVD + 1280 + kvh * 64 + d];
    }
    __syncthreads();
    for (int e = tid; e < 64 * 64; e += 256) {
        int d = e >> 6, tl = e & 63;
        vt[((size_t)(b * KVHN + kvh) * 64 + d) * TT + t0 + tl] = __float2bfloat16(Ls[tl][d]);
    }
}

// ---------------- MFMA flash attention (bf16, causal, GQA h%4) ------------
__global__ __launch_bounds__(256) void attn_mfma_k(const bf16* __restrict__ qp,
                                                   const bf16* __restrict__ kp,
                                                   const bf16* __restrict__ vt,
                                                   bf16* __restrict__ y) {
    int qt = blockIdx.x;
    int h = blockIdx.y;
    int b = blockIdx.z;
    int kvh = h & (KVHN - 1);

    __shared__ __align__(16) bf16 Ks[64][KSTR];
    __shared__ __align__(16) bf16 Vt[64][KSTR];       // [d][k]
    __shared__ __align__(16) bf16 Ps[4][16][KSTR];    // per-wave P[q][k]

    int tid = threadIdx.x;
    int lane = tid & 63;
    int w = tid >> 6;
    int qi = lane & 15;
    int g = lane >> 4;

    const bf16* qbase = qp + (((size_t)(b * NH + h) * TT + qt * 64 + w * 16 + qi) * 64);
    bf16x8 qf0 = *(const bf16x8*)(qbase + g * 8);
    bf16x8 qf1 = *(const bf16x8*)(qbase + 32 + g * 8);

    const bf16* kg = kp + ((size_t)(b * KVHN + kvh) * TT) * 64;
    const bf16* vg = vt + ((size_t)(b * KVHN + kvh) * 64) * TT;

    f32x4 oacc[4] = {};
    float m = -INFINITY, l = 0.0f;
    int qglob = qt * 64 + w * 16 + qi;

    for (int kt = 0; kt <= qt; ++kt) {
        __syncthreads();
        {
            int c0 = tid, c1 = tid + 256;
            *(bf16x8*)(&Ks[c0 >> 3][(c0 & 7) * 8]) =
                *(const bf16x8*)(kg + (size_t)(kt * 64 + (c0 >> 3)) * 64 + (c0 & 7) * 8);
            *(bf16x8*)(&Ks[c1 >> 3][(c1 & 7) * 8]) =
                *(const bf16x8*)(kg + (size_t)(kt * 64 + (c1 >> 3)) * 64 + (c1 & 7) * 8);
            *(bf16x8*)(&Vt[c0 >> 3][(c0 & 7) * 8]) =
                *(const bf16x8*)(vg + (size_t)(c0 >> 3) * TT + kt * 64 + (c0 & 7) * 8);
            *(bf16x8*)(&Vt[c1 >> 3][(c1 & 7) * 8]) =
                *(const bf16x8*)(vg + (size_t)(c1 >> 3) * TT + kt * 64 + (c1 & 7) * 8);
        }
        __syncthreads();

        f32x4 sacc[4] = {};
#pragma unroll
        for (int stt = 0; stt < 4; ++stt) {
            bf16x8 kf0 = *(const bf16x8*)(&Ks[stt * 16 + qi][g * 8]);
            bf16x8 kf1 = *(const bf16x8*)(&Ks[stt * 16 + qi][32 + g * 8]);
            sacc[stt] = __builtin_amdgcn_mfma_f32_16x16x32_bf16(kf0, qf0, sacc[stt], 0, 0, 0);
            sacc[stt] = __builtin_amdgcn_mfma_f32_16x16x32_bf16(kf1, qf1, sacc[stt], 0, 0, 0);
        }

        if (kt == qt) {
#pragma unroll
            for (int stt = 0; stt < 4; ++stt)
#pragma unroll
                for (int r = 0; r < 4; ++r) {
                    int kgl = kt * 64 + stt * 16 + g * 4 + r;
                    if (kgl > qglob) sacc[stt][r] = -INFINITY;
                }
        }

        float tmax = -INFINITY;
#pragma unroll
        for (int stt = 0; stt < 4; ++stt)
#pragma unroll
            for (int r = 0; r < 4; ++r) tmax = fmaxf(tmax, sacc[stt][r]);
        tmax = fmaxf(tmax, __shfl_xor(tmax, 16));
        tmax = fmaxf(tmax, __shfl_xor(tmax, 32));
        float mnew = fmaxf(m, tmax);
        float scale = __expf(m - mnew);
        float psum = 0.0f;
#pragma unroll
        for (int stt = 0; stt < 4; ++stt) {
            bf16 pb[4];
#pragma unroll
            for (int r = 0; r < 4; ++r) {
                float p = __expf(sacc[stt][r] - mnew);
                psum += p;
                pb[r] = __float2bfloat16(p);
            }
            *(uint2*)(&Ps[w][qi][stt * 16 + g * 4]) = *(uint2*)pb;
        }
        psum += __shfl_xor(psum, 16);
        psum += __shfl_xor(psum, 32);
        l = l * scale + psum;
        m = mnew;

        float sc0 = __shfl(scale, g * 4 + 0);
        float sc1 = __shfl(scale, g * 4 + 1);
        float sc2 = __shfl(scale, g * 4 + 2);
        float sc3 = __shfl(scale, g * 4 + 3);
#pragma unroll
        for (int dt = 0; dt < 4; ++dt) {
            oacc[dt][0] *= sc0; oacc[dt][1] *= sc1;
            oacc[dt][2] *= sc2; oacc[dt][3] *= sc3;
        }

#pragma unroll
        for (int kc = 0; kc < 2; ++kc) {
            bf16x8 pa = *(const bf16x8*)(&Ps[w][qi][kc * 32 + g * 8]);
#pragma unroll
            for (int dt = 0; dt < 4; ++dt) {
                bf16x8 vb = *(const bf16x8*)(&Vt[dt * 16 + qi][kc * 32 + g * 8]);
                oacc[dt] = __builtin_amdgcn_mfma_f32_16x16x32_bf16(pa, vb, oacc[dt], 0, 0, 0);
            }
        }
    }

    float linv = 1.0f / l;
    float li0 = __shfl(linv, g * 4 + 0);
    float li1 = __shfl(linv, g * 4 + 1);
    float li2 = __shfl(linv, g * 4 + 2);
    float li3 = __shfl(linv, g * 4 + 3);
#pragma unroll
    for (int dt = 0; dt < 4; ++dt) {
        int dcol = h * 64 + dt * 16 + qi;
        size_t r0 = (size_t)(b * TT + qt * 64 + w * 16 + g * 4) * DD + dcol;
        y[r0 + 0 * DD] = __float2bfloat16(oacc[dt][0] * li0);
        y[r0 + 1 * DD] = __float2bfloat16(oacc[dt][1] * li1);
        y[r0 + 2 * DD] = __float2bfloat16(oacc[dt][2] * li2);
        y[r0 + 3 * DD] = __float2bfloat16(oacc[dt][3] * li3);
    }
}

// ---------------- silu(g)*u from fused gu (bf16) -> gb (bf16), x4 vec ------
__global__ void silu_mul_k(const bf16* __restrict__ gu, bf16* __restrict__ gb) {
    int i4 = blockIdx.x * 256 + threadIdx.x;
    if (i4 >= NTOK * IIP / 4) return;
    int i = i4 * 4;
    int r = i / IIP, c = i - r * IIP;
    ushort4 gv = *(const ushort4*)(gu + (size_t)r * (2 * IIP) + c);
    ushort4 uv = *(const ushort4*)(gu + (size_t)r * (2 * IIP) + IIP + c);
    ushort4 o;
    {
        float g0 = b2f(gv.x); o.x = f2b(g0 / (1.0f + __expf(-g0)) * b2f(uv.x));
        float g1 = b2f(gv.y); o.y = f2b(g1 / (1.0f + __expf(-g1)) * b2f(uv.y));
        float g2 = b2f(gv.z); o.z = f2b(g2 / (1.0f + __expf(-g2)) * b2f(uv.z));
        float g3 = b2f(gv.w); o.w = f2b(g3 / (1.0f + __expf(-g3)) * b2f(uv.w));
    }
    *(ushort4*)(gb + i) = o;
}

// ---------------- fp32 -> bf16 convert with row/col zero-padding, x4 vec ---
__device__ inline void cvt_body(const float* __restrict__ src, bf16* __restrict__ dst,
                                int Msrc, int Ksrc, int Kdst, int total4,
                                int start, int stride) {
    for (int i4 = start; i4 < total4; i4 += stride) {
        int i = i4 * 4;
        int r = i / Kdst, c = i - r * Kdst;
        ushort4 o;
        if (r < Msrc && c + 4 <= Ksrc && (Ksrc & 3) == 0) {
            float4 v = *(const float4*)(src + (size_t)r * Ksrc + c);
            o.x = f2b(v.x); o.y = f2b(v.y); o.z = f2b(v.z); o.w = f2b(v.w);
        } else {
            float v0 = (r < Msrc && c + 0 < Ksrc) ? src[(size_t)r * Ksrc + c + 0] : 0.0f;
            float v1 = (r < Msrc && c + 1 < Ksrc) ? src[(size_t)r * Ksrc + c + 1] : 0.0f;
            float v2 = (r < Msrc && c + 2 < Ksrc) ? src[(size_t)r * Ksrc + c + 2] : 0.0f;
            float v3 = (r < Msrc && c + 3 < Ksrc) ? src[(size_t)r * Ksrc + c + 3] : 0.0f;
            o.x = f2b(v0); o.y = f2b(v1); o.z = f2b(v2); o.w = f2b(v3);
        }
        *(ushort4*)(dst + i) = o;
    }
}

__global__ void cvt_pad_k(const float* __restrict__ src, bf16* __restrict__ dst,
                          int Msrc, int Ksrc, int Kdst, int total4) {
    cvt_body(src, dst, Msrc, Ksrc, Kdst, total4,
             blockIdx.x * 256 + threadIdx.x, gridDim.x * 256);
}

// fused per-layer weight conversion: 6 jobs via blockIdx.y
struct CvtJobs {
    const float* src[6];
    bf16* dst[6];
    int Msrc[6], Ksrc[6], Kdst[6], n4[6];
};
__global__ void cvt_fused_k(CvtJobs j) {
    int job = blockIdx.y;
    cvt_body(j.src[job], j.dst[job], j.Msrc[job], j.Ksrc[job], j.Kdst[job],
             j.n4[job], blockIdx.x * 256 + threadIdx.x, gridDim.x * 256);
}

// ---------------- bf16 MFMA GEMM: C[N,M] = A[N,K] @ W[M,K]^T ----------------
// m97 structure: 128-row (N) tile x BN-col (M) tile, BK=32, 4 waves, 16x16x32.
// BN=128: 4x4 frags, supertile(2m x 16n) + XCD-chunk decode (nwg % 32 == 0).
// BN=64:  4x2 frags, n-fastest + XCD-chunk decode (nwg % 8 == 0).
// MODE 0: C fp32; MODE 1: C fp32 += res; MODE 2: C bf16.
template <int MODE, int BN>
__global__ __launch_bounds__(256) void gemm_bt(const bf16* __restrict__ A,
                                               const bf16* __restrict__ W,
                                               const float* res, void* Cv,
                                               int N, int M, int K) {
    constexpr int NF = (BN == 128) ? 4 : 2;
    __shared__ __align__(16) bf16 As[128 * 32];
    __shared__ __align__(16) bf16 Bs[BN * 32];

    int t = threadIdx.x;
    int nnt = N >> 7;
    int nmt = (BN == 128) ? (M >> 7) : (M >> 6);
    int nwg = nmt * nnt;
    int orig = blockIdx.x;
    int q8 = nwg >> 3;
    int wgid = (orig & 7) * q8 + (orig >> 3);   // XCD-chunked, bijective
    int mt, nt;
    if (BN == 128) {                             // supertile: 2 m-tiles x nnt
        int stile = wgid >> 5, rem = wgid & 31;
        mt = (stile << 1) + (rem & 1);
        nt = rem >> 1;
    } else {
        mt = wgid / nnt;
        nt = wgid - mt * nnt;
    }
    int m0 = mt * BN;
    int n0 = nt * 128;

    int lane = t & 63;
    int wave = t >> 6;
    int wr = (wave >> 1) * 64;
    int wc = (wave & 1) * (BN / 2);

    int c1 = t, c2 = t + 256;
    const bf16* gA1 = A + (size_t)(n0 + (c1 >> 2)) * K + ((c1 & 3) * 8);
    const bf16* gA2 = A + (size_t)(n0 + (c2 >> 2)) * K + ((c2 & 3) * 8);
    const bf16* gB1 = W + (size_t)(m0 + (c1 >> 2)) * K + ((c1 & 3) * 8);
    const bf16* gB2 = W + (size_t)(m0 + (c2 >> 2)) * K + ((c2 & 3) * 8);

    f32x4 acc[4][NF] = {};

    for (int k0 = 0; k0 < K; k0 += 32) {
        __syncthreads();
        GLOAD16(gA1 + k0, As + c1 * 8);
        GLOAD16(gA2 + k0, As + c2 * 8);
        GLOAD16(gB1 + k0, Bs + c1 * 8);
        if (BN == 128) GLOAD16(gB2 + k0, Bs + c2 * 8);
        __syncthreads();

        bf16x8 af[4], bfr[NF];
#pragma unroll
        for (int m = 0; m < 4; m++)
            af[m] = *(const bf16x8*)(As + (wr + m * 16 + (lane & 15)) * 32 + (lane >> 4) * 8);
#pragma unroll
        for (int n = 0; n < NF; n++)
            bfr[n] = *(const bf16x8*)(Bs + (wc + n * 16 + (lane & 15)) * 32 + (lane >> 4) * 8);
#pragma unroll
        for (int m = 0; m < 4; m++)
#pragma unroll
            for (int n = 0; n < NF; n++)
                acc[m][n] = __builtin_amdgcn_mfma_f32_16x16x32_bf16(af[m], bfr[n], acc[m][n], 0, 0, 0);
    }

    float* Cf = (float*)Cv;
    bf16* Cb = (bf16*)Cv;
    int colb = m0 + wc + (lane & 15);
    int rowb = n0 + wr + (lane >> 4) * 4;
#pragma unroll
    for (int m = 0; m < 4; m++) {
#pragma unroll
        for (int n = 0; n < NF; n++) {
#pragma unroll
            for (int r = 0; r < 4; r++) {
                size_t off = (size_t)(rowb + m * 16 + r) * M + (colb + n * 16);
                float v = acc[m][n][r];
                if (MODE == 0) Cf[off] = v;
                if (MODE == 1) Cf[off] = v + res[off];
                if (MODE == 2) Cb[off] = __float2bfloat16(v);
            }
        }
    }
}

static inline int cvtgrid(int total) {
    int g = (total + 255) / 256;
    return g > 2048 ? 2048 : g;
}

extern "C" void kernel_launch(void* const* d_in, const int* in_sizes, int n_in,
                              void* d_out, int out_size, void* d_ws, size_t ws_size,
                              hipStream_t stream) {
    const int* idx    = (const int*)d_in[0];
    const float* wte  = (const float*)d_in[1];
    const float* Wq   = (const float*)d_in[2];
    const float* Wkv  = (const float*)d_in[3];
    const float* Wo   = (const float*)d_in[4];
    const float* Wg   = (const float*)d_in[5];
    const float* Wu   = (const float*)d_in[6];
    const float* Wd   = (const float*)d_in[7];
    const float* rms1 = (const float*)d_in[8];
    const float* rms2 = (const float*)d_in[9];
    const float* rmsf = (const float*)d_in[10];
    float* out = (float*)d_out;

    char* ws = (char*)d_ws;
    size_t off = 0;
    float* x = (float*)(ws + off);  off += (size_t)NTOK * DD * 4;
    bf16* xn = (bf16*)(ws + off);   off += (size_t)NTOK * DD * 2;
    float* st = (float*)(ws + off); off += (size_t)TT * 64 * 4;
    float* ct = (float*)(ws + off); off += (size_t)TT * 64 * 4;
    char* region = ws + off;
    size_t roff = 0;
    float* qkv = (float*)(region + roff);    roff += (size_t)NTOK * QKVD * 4;
    bf16* yb = (bf16*)(region + roff);       roff += (size_t)NTOK * DD * 2;
    bf16* gu = (bf16*)(region + roff);       roff += (size_t)NTOK * 2 * IIP * 2;
    bf16* gb = (bf16*)(region + roff);       roff += (size_t)NTOK * IIP * 2;
    bf16* Wqkv_buf = (bf16*)(region + roff); roff += (size_t)QKVD * DD * 2;
    bf16* Wo_buf = (bf16*)(region + roff);   roff += (size_t)DD * DD * 2;
    bf16* Wgu_buf = (bf16*)(region + roff);  roff += (size_t)2 * IIP * DD * 2;
    bf16* Wd_buf = (bf16*)(region + roff);   roff += (size_t)DD * IIP * 2;
    bf16* qp = gu;                                    // aliases (gu dead here)
    bf16* kp = qp + (size_t)NTOK * DD;
    bf16* vt = kp + (size_t)BB * KVHN * TT * 64;
    bf16* wte_bf = (bf16*)region;  // reuses whole region AFTER the layer loop

    rope_table_k<<<(TT * 64 + 255) / 256, 256, 0, stream>>>(st, ct);
    embed_k<<<NTOK, 256, 0, stream>>>(idx, wte, x);

    for (int l = 0; l < NL; ++l) {
        // fused weight conversion (6 jobs), before any GEMM of this layer
        CvtJobs j;
        j.src[0] = Wq + (size_t)l * DD * DD;   j.dst[0] = Wqkv_buf;
        j.Msrc[0] = DD;  j.Ksrc[0] = DD;  j.Kdst[0] = DD;  j.n4[0] = DD * DD / 4;
        j.src[1] = Wkv + (size_t)l * 512 * DD; j.dst[1] = Wqkv_buf + (size_t)DD * DD;
        j.Msrc[1] = 512; j.Ksrc[1] = DD;  j.Kdst[1] = DD;  j.n4[1] = 512 * DD / 4;
        j.src[2] = Wo + (size_t)l * DD * DD;   j.dst[2] = Wo_buf;
        j.Msrc[2] = DD;  j.Ksrc[2] = DD;  j.Kdst[2] = DD;  j.n4[2] = DD * DD / 4;
        j.src[3] = Wg + (size_t)l * II * DD;   j.dst[3] = Wgu_buf;
        j.Msrc[3] = II;  j.Ksrc[3] = DD;  j.Kdst[3] = DD;  j.n4[3] = IIP * DD / 4;
        j.src[4] = Wu + (size_t)l * II * DD;   j.dst[4] = Wgu_buf + (size_t)IIP * DD;
        j.Msrc[4] = II;  j.Ksrc[4] = DD;  j.Kdst[4] = DD;  j.n4[4] = IIP * DD / 4;
        j.src[5] = Wd + (size_t)l * DD * II;   j.dst[5] = Wd_buf;
        j.Msrc[5] = DD;  j.Ksrc[5] = II;  j.Kdst[5] = IIP; j.n4[5] = DD * IIP / 4;
        cvt_fused_k<<<dim3(512, 6), 256, 0, stream>>>(j);

        // --- attention block ---
        rmsnorm_k<<<NTOK, 256, 0, stream>>>(x, rms1 + (size_t)l * DD, xn);
        gemm_bt<0, 64><<<(QKVD / 64) * (NTOK / 128), 256, 0, stream>>>(
            xn, Wqkv_buf, nullptr, qkv, NTOK, QKVD, DD);
        pack_qk_k<<<(NTOK * 20 * 32 + 255) / 256, 256, 0, stream>>>(qkv, st, ct, qp, kp);
        pack_v_k<<<dim3(TT / 64, KVHN, BB), 256, 0, stream>>>(qkv, vt);
        attn_mfma_k<<<dim3(TT / 64, NH, BB), 256, 0, stream>>>(qp, kp, vt, yb);
        gemm_bt<1, 64><<<(DD / 64) * (NTOK / 128), 256, 0, stream>>>(
            yb, Wo_buf, x, x, NTOK, DD, DD);
        // --- mlp block ---
        rmsnorm_k<<<NTOK, 256, 0, stream>>>(x, rms2 + (size_t)l * DD, xn);
        gemm_bt<2, 128><<<(2 * IIP / 128) * (NTOK / 128), 256, 0, stream>>>(
            xn, Wgu_buf, nullptr, gu, NTOK, 2 * IIP, DD);
        silu_mul_k<<<(NTOK * IIP / 4 + 255) / 256, 256, 0, stream>>>(gu, gb);
        gemm_bt<1, 64><<<(DD / 64) * (NTOK / 128), 256, 0, stream>>>(
            gb, Wd_buf, x, x, NTOK, DD, IIP);
    }

    // --- final norm + tied lm_head ---
    rmsnorm_k<<<NTOK, 256, 0, stream>>>(x, rmsf, xn);
    cvt_pad_k<<<2048, 256, 0, stream>>>(wte, wte_bf, 32000, DD, DD, 32000 * DD / 4);
    gemm_bt<0, 128><<<(32000 / 128) * (NTOK / 128), 256, 0, stream>>>(
        xn, wte_bf, nullptr, out, NTOK, 32000, DD);
}